// Round 2
// baseline (4693.944 us; speedup 1.0000x reference)
//
#include <hip/hip_runtime.h>
#include <hip/hip_bf16.h>

#define S_   1024
#define B_   4
#define D_   1024
#define H_   16
#define HD_  64
#define DFF_ 4096
#define NREL 101
#define MROWS (S_*B_)

__device__ __forceinline__ float wave_red_sum(float v) {
#pragma unroll
  for (int o = 32; o; o >>= 1) v += __shfl_xor(v, o, 64);
  return v;
}
__device__ __forceinline__ float wave_red_max(float v) {
#pragma unroll
  for (int o = 32; o; o >>= 1) v = fmaxf(v, __shfl_xor(v, o, 64));
  return v;
}

// ---------------- RMSNorm (optionally transposing [S,B,D] -> [B,S,D]) ----------------
template<bool TO_BSD>
__global__ __launch_bounds__(256) void rmsnorm_kernel(
    const float* __restrict__ x, const float* __restrict__ g, float* __restrict__ y) {
  const int row = blockIdx.x;                 // row index in INPUT layout
  const float* xr = x + (size_t)row * D_;
  int orow;
  if (TO_BSD) { int s = row / B_, b = row - s * B_; orow = b * S_ + s; }
  else        { orow = row; }
  float* yr = y + (size_t)orow * D_;

  float ss = 0.f;
  for (int i = threadIdx.x; i < D_; i += 256) { float v = xr[i]; ss += v * v; }
  ss = wave_red_sum(ss);
  __shared__ float red[4];
  if ((threadIdx.x & 63) == 0) red[threadIdx.x >> 6] = ss;
  __syncthreads();
  float tot = red[0] + red[1] + red[2] + red[3];
  float rms = sqrtf(tot) * (1.f / 32.f);      // norm * D^-0.5  (sqrt(1024)=32)
  float inv = 1.f / (rms + 1e-8f);
  for (int i = threadIdx.x; i < D_; i += 256) yr[i] = g[i] * (xr[i] * inv);
}

// ---------------- Generic tiled f32 GEMM:  Y[M,N] = X[M,K] * W[N,K]^T + bias ----------------
// MODE 0: Y = acc + bias
// MODE 1: Y = acc + bias + resid            (O-proj residual, write h2)
// MODE 2: Y = gelu(acc + bias)              (FFN up)
// MODE 3: out[(s*B+b)*D+col] = acc+bias+resid[row]   (final, transposed store)
template<int MODE>
__global__ __launch_bounds__(256) void gemm_kernel(
    const float* __restrict__ X, const float* __restrict__ W,
    const float* __restrict__ bias, const float* __restrict__ resid,
    float* __restrict__ Y, int N, int K) {
  __shared__ float As[16][68];
  __shared__ float Bs[16][68];
  const int bm = blockIdx.x * 64, bn = blockIdx.y * 64;
  const int tid = threadIdx.x;
  const int tx = tid & 15, ty = tid >> 4;
  const int lm = tid >> 2, lk4 = (tid & 3) * 4;

  float acc[4][4] = {};
  const float* Xp = X + (size_t)(bm + lm) * K + lk4;
  const float* Wp = W + (size_t)(bn + lm) * K + lk4;

  for (int k0 = 0; k0 < K; k0 += 16) {
    float4 xa = *(const float4*)(Xp + k0);
    float4 wb = *(const float4*)(Wp + k0);
    As[lk4 + 0][lm] = xa.x; As[lk4 + 1][lm] = xa.y; As[lk4 + 2][lm] = xa.z; As[lk4 + 3][lm] = xa.w;
    Bs[lk4 + 0][lm] = wb.x; Bs[lk4 + 1][lm] = wb.y; Bs[lk4 + 2][lm] = wb.z; Bs[lk4 + 3][lm] = wb.w;
    __syncthreads();
#pragma unroll
    for (int kk = 0; kk < 16; ++kk) {
      float4 a = *(const float4*)(&As[kk][ty * 4]);
      float4 b = *(const float4*)(&Bs[kk][tx * 4]);
      float ar[4] = {a.x, a.y, a.z, a.w};
      float br[4] = {b.x, b.y, b.z, b.w};
#pragma unroll
      for (int r = 0; r < 4; ++r)
#pragma unroll
        for (int c = 0; c < 4; ++c) acc[r][c] += ar[r] * br[c];
    }
    __syncthreads();
  }

  const int row0 = bm + ty * 4, col0 = bn + tx * 4;
#pragma unroll
  for (int r = 0; r < 4; ++r) {
    const int row = row0 + r;
#pragma unroll
    for (int c = 0; c < 4; ++c) {
      const int col = col0 + c;
      float v = acc[r][c] + bias[col];
      if constexpr (MODE == 2) v = 0.5f * v * (1.f + erff(v * 0.70710678118654752f));
      if constexpr (MODE == 1 || MODE == 3) v += resid[(size_t)row * N + col];
      if constexpr (MODE == 3) {
        const int b = row >> 10, s = row & (S_ - 1);     // row = b*S+s
        Y[((size_t)(s * B_ + b)) * D_ + col] = v;
      } else {
        Y[(size_t)row * N + col] = v;
      }
    }
  }
}

// ---------------- Fused relative attention ----------------
// grid: (S/8, B*H). Each block: 8 q-rows of one (b,h). 4 waves, 2 rows/wave.
__global__ __launch_bounds__(256) void attn_kernel(
    const float* __restrict__ Q, const float* __restrict__ K,
    const float* __restrict__ V, const float* __restrict__ relk,
    const float* __restrict__ relv, float* __restrict__ Wctx) {
  __shared__ float sc[8][S_];        // 32 KB: score rows -> p rows
  __shared__ float qs[8][HD_];       // 2 KB
  __shared__ float qrel[8][NREL];    // 3.2 KB
  __shared__ float tile[NREL][65];   // 26.3 KB: K-tile (rows 0..63) then rel_v

  const int q0 = blockIdx.x * 8;
  const int bh = blockIdx.y;
  const int b = bh >> 4, h = bh & 15;
  const int tid = threadIdx.x;
  const int w = tid >> 6, lane = tid & 63;

  // stage 8 q rows
  for (int idx = tid; idx < 8 * HD_; idx += 256) {
    int i = idx >> 6, d = idx & 63;
    qs[i][d] = Q[((size_t)(b * S_ + q0 + i)) * D_ + h * HD_ + d];
  }
  __syncthreads();

  // qrel[i][r] = qs[i] . relk[r]
  for (int p = w; p < 8 * NREL; p += 4) {
    int i = p / NREL, r = p - i * NREL;
    float v = qs[i][lane] * relk[r * HD_ + lane];
    v = wave_red_sum(v);
    if (lane == 0) qrel[i][r] = v;
  }
  __syncthreads();

  // scores: loop K tiles of 64 rows
  for (int kt = 0; kt < S_ / 64; ++kt) {
    const int k0 = kt * 64;
    __syncthreads();   // tile reuse protection
    // stage full 64x64 K-tile: 4096 floats = 4 float4 per thread
    for (int idx = tid; idx < 64 * 16; idx += 256) {
      const int kk = idx >> 4, dv = (idx & 15) * 4;
      float4 kv = *(const float4*)(K + ((size_t)(b * S_ + k0 + kk)) * D_ + h * HD_ + dv);
      tile[kk][dv + 0] = kv.x; tile[kk][dv + 1] = kv.y;
      tile[kk][dv + 2] = kv.z; tile[kk][dv + 3] = kv.w;
    }
    __syncthreads();
#pragma unroll
    for (int ii = 0; ii < 2; ++ii) {
      const int i = w * 2 + ii;
      float dot = 0.f;
#pragma unroll 16
      for (int d = 0; d < HD_; ++d) dot += qs[i][d] * tile[lane][d];
      const int k = k0 + lane;
      const int dist = k - (q0 + i);
      const int ridx = min(max(dist, -50), 50) + 50;
      sc[i][k] = (dot + qrel[i][ridx]) * 0.125f;
    }
  }
  __syncthreads();

  // softmax (each wave: its 2 rows)
#pragma unroll
  for (int ii = 0; ii < 2; ++ii) {
    const int i = w * 2 + ii;
    float m = -1e30f;
#pragma unroll
    for (int j = 0; j < 16; ++j) m = fmaxf(m, sc[i][lane + j * 64]);
    m = wave_red_max(m);
    float sum = 0.f;
#pragma unroll
    for (int j = 0; j < 16; ++j) {
      float e = __expf(sc[i][lane + j * 64] - m);
      sc[i][lane + j * 64] = e;
      sum += e;
    }
    sum = wave_red_sum(sum);
    const float inv = 1.f / sum;
#pragma unroll
    for (int j = 0; j < 16; ++j) sc[i][lane + j * 64] *= inv;
  }
  __syncthreads();

  // stage rel_v into tile
  for (int idx = tid; idx < NREL * HD_; idx += 256)
    tile[idx >> 6][idx & 63] = relv[idx];
  __syncthreads();

  // PV: w[d] = sum_k p[k] * (V[k,d] + rel_v[clip(k-q)+50, d])
  const float* Vb = V + ((size_t)b * S_) * D_ + h * HD_ + lane;
  const int i0 = w * 2;
  const float* p0 = sc[i0];
  const float* p1 = sc[i0 + 1];
  float acc0 = 0.f, acc1 = 0.f;
#pragma unroll 4
  for (int k = 0; k < S_; ++k) {
    const float v = Vb[(size_t)k * D_];
    const int d0 = k - (q0 + i0);
    const int r0 = min(max(d0, -50), 50) + 50;
    const int r1 = min(max(d0 - 1, -50), 50) + 50;
    acc0 += p0[k] * (v + tile[r0][lane]);
    acc1 += p1[k] * (v + tile[r1][lane]);
  }
  Wctx[((size_t)(b * S_ + q0 + i0)) * D_ + h * HD_ + lane] = acc0;
  Wctx[((size_t)(b * S_ + q0 + i0 + 1)) * D_ + h * HD_ + lane] = acc1;
}

// ---------------- launch ----------------
extern "C" void kernel_launch(void* const* d_in, const int* in_sizes, int n_in,
                              void* d_out, int out_size, void* d_ws, size_t ws_size,
                              hipStream_t stream) {
  (void)in_sizes; (void)n_in; (void)out_size; (void)ws_size;
  const float* x      = (const float*)d_in[0];
  const float* Wq     = (const float*)d_in[1];
  const float* bq     = (const float*)d_in[2];
  const float* Wk     = (const float*)d_in[3];
  const float* bk     = (const float*)d_in[4];
  const float* Wv     = (const float*)d_in[5];
  const float* bv     = (const float*)d_in[6];
  const float* Wo     = (const float*)d_in[7];
  const float* bo     = (const float*)d_in[8];
  const float* rel_k  = (const float*)d_in[9];
  const float* rel_v  = (const float*)d_in[10];
  const float* g_attn = (const float*)d_in[11];
  const float* g_ff   = (const float*)d_in[12];
  const float* W_in   = (const float*)d_in[13];
  const float* b_in   = (const float*)d_in[14];
  const float* W_out  = (const float*)d_in[15];
  const float* b_out  = (const float*)d_in[16];
  float* out = (float*)d_out;

  const size_t NE = (size_t)MROWS * D_;     // 4M elements
  float* hb   = (float*)d_ws;               // [B,S,D]  rmsnorm(x), kept for residual
  float* qbuf = hb + NE;                    // Q  -> later h2
  float* kbuf = qbuf + NE;                  // K  -> later f (rmsnorm2)
  float* vbuf = kbuf + NE;                  // V
  float* wbuf = vbuf + NE;                  // attn context [B,S,D]
  float* ff1  = wbuf + NE;                  // [4096, 4096]

  // 1. pre-norm + transpose to [B,S,D]
  hipLaunchKernelGGL((rmsnorm_kernel<true>), dim3(MROWS), dim3(256), 0, stream, x, g_attn, hb);
  // 2. QKV projections
  dim3 g1(MROWS / 64, D_ / 64);
  hipLaunchKernelGGL((gemm_kernel<0>), g1, dim3(256), 0, stream, hb, Wq, bq, nullptr, qbuf, D_, D_);
  hipLaunchKernelGGL((gemm_kernel<0>), g1, dim3(256), 0, stream, hb, Wk, bk, nullptr, kbuf, D_, D_);
  hipLaunchKernelGGL((gemm_kernel<0>), g1, dim3(256), 0, stream, hb, Wv, bv, nullptr, vbuf, D_, D_);
  // 3. fused relative attention
  hipLaunchKernelGGL(attn_kernel, dim3(S_ / 8, B_ * H_), dim3(256), 0, stream,
                     qbuf, kbuf, vbuf, rel_k, rel_v, wbuf);
  // 4. O-proj + residual -> h2 (into qbuf)
  hipLaunchKernelGGL((gemm_kernel<1>), g1, dim3(256), 0, stream, wbuf, Wo, bo, hb, qbuf, D_, D_);
  // 5. second rmsnorm -> f (into kbuf)
  hipLaunchKernelGGL((rmsnorm_kernel<false>), dim3(MROWS), dim3(256), 0, stream, qbuf, g_ff, kbuf);
  // 6. FFN up + gelu
  dim3 g2(MROWS / 64, DFF_ / 64);
  hipLaunchKernelGGL((gemm_kernel<2>), g2, dim3(256), 0, stream, kbuf, W_in, b_in, nullptr, ff1, DFF_, D_);
  // 7. FFN down + residual + transposed store to [S,B,D]
  hipLaunchKernelGGL((gemm_kernel<3>), g1, dim3(256), 0, stream, ff1, W_out, b_out, qbuf, out, D_, DFF_);
}

// Round 3
// 2446.954 us; speedup vs baseline: 1.9183x; 1.9183x over previous
//
#include <hip/hip_runtime.h>
#include <hip/hip_bf16.h>

#define S_   1024
#define B_   4
#define D_   1024
#define H_   16
#define HD_  64
#define DFF_ 4096
#define NREL 101
#define MROWS (S_*B_)

typedef __attribute__((ext_vector_type(8))) short bf16x8;
typedef __attribute__((ext_vector_type(4))) float f32x4;
typedef __attribute__((ext_vector_type(8))) unsigned short u16x8;

__device__ __forceinline__ float b2f(unsigned short u) {
  unsigned int v = ((unsigned int)u) << 16;
  return __builtin_bit_cast(float, v);
}
__device__ __forceinline__ unsigned short f2b(float f) {
  unsigned int v = __builtin_bit_cast(unsigned int, f);
  v += 0x7fffu + ((v >> 16) & 1u);
  return (unsigned short)(v >> 16);
}

__device__ __forceinline__ float wave_red_sum(float v) {
#pragma unroll
  for (int o = 32; o; o >>= 1) v += __shfl_xor(v, o, 64);
  return v;
}
__device__ __forceinline__ float wave_red_max(float v) {
#pragma unroll
  for (int o = 32; o; o >>= 1) v = fmaxf(v, __shfl_xor(v, o, 64));
  return v;
}

__device__ __forceinline__ void gload_lds16(const void* g, void* l) {
  __builtin_amdgcn_global_load_lds(
      (const __attribute__((address_space(1))) void*)g,
      (__attribute__((address_space(3))) void*)l, 16, 0, 0);
}

// ---------------- f32 -> bf16 convert ----------------
__global__ __launch_bounds__(256) void cvt_kernel(
    const float* __restrict__ s, unsigned short* __restrict__ d, int n) {
  int i = (blockIdx.x * 256 + threadIdx.x) * 4;
  if (i >= n) return;
  float4 v = *(const float4*)(s + i);
  ushort4 o; o.x = f2b(v.x); o.y = f2b(v.y); o.z = f2b(v.z); o.w = f2b(v.w);
  *(ushort4*)(d + i) = o;
}

// ---------------- RMSNorm: f32 in -> bf16 out (+ optional f32 out) ----------------
template<bool TO_BSD, bool WF32>
__global__ __launch_bounds__(256) void rmsnorm_kernel(
    const float* __restrict__ x, const float* __restrict__ g,
    unsigned short* __restrict__ yb, float* __restrict__ yf) {
  const int row = blockIdx.x;
  int orow = row;
  if (TO_BSD) { int s = row >> 2, b = row & 3; orow = b * S_ + s; }  // row = s*B+b
  const float4 v = *(const float4*)(x + (size_t)row * D_ + threadIdx.x * 4);
  float ss = v.x * v.x + v.y * v.y + v.z * v.z + v.w * v.w;
  ss = wave_red_sum(ss);
  __shared__ float red[4];
  if ((threadIdx.x & 63) == 0) red[threadIdx.x >> 6] = ss;
  __syncthreads();
  const float tot = red[0] + red[1] + red[2] + red[3];
  const float inv = 1.f / (sqrtf(tot) * (1.f / 32.f) + 1e-8f);
  const float4 gg = *(const float4*)(g + threadIdx.x * 4);
  const float o0 = gg.x * v.x * inv, o1 = gg.y * v.y * inv;
  const float o2 = gg.z * v.z * inv, o3 = gg.w * v.w * inv;
  const size_t ob = (size_t)orow * D_ + threadIdx.x * 4;
  ushort4 ub; ub.x = f2b(o0); ub.y = f2b(o1); ub.z = f2b(o2); ub.w = f2b(o3);
  *(ushort4*)(yb + ob) = ub;
  if (WF32) { float4 of = make_float4(o0, o1, o2, o3); *(float4*)(yf + ob) = of; }
}

// ---------------- bf16 MFMA GEMM (m97 structure): Y[M,N] = X[M,K] * W[N,K]^T + bias ----------------
// MODE 0: bf16 out = acc + bias                       (QKV)
// MODE 1: f32  out = acc + bias + resid               (O-proj -> h2)
// MODE 2: bf16 out = gelu(acc + bias)                 (FFN up)
// MODE 3: f32  out[(s*B+b)*D+col] = acc+bias+resid    (final, transposed store)
template<int MODE>
__global__ __launch_bounds__(256) void gemm_bf16(
    const unsigned short* __restrict__ X, const unsigned short* __restrict__ Wt,
    const float* __restrict__ bias, const float* __restrict__ resid,
    void* __restrict__ Yv, int N, int K) {
  __shared__ __align__(16) unsigned short As[128 * 32];
  __shared__ __align__(16) unsigned short Bs[128 * 32];
  const int tid = threadIdx.x;
  const int wid = tid >> 6, lane = tid & 63;
  const int bm = blockIdx.x * 128, bn = blockIdx.y * 128;
  const int wr = wid >> 1, wc = wid & 1;

  f32x4 acc[4][4];
#pragma unroll
  for (int m = 0; m < 4; ++m)
#pragma unroll
    for (int n = 0; n < 4; ++n) acc[m][n] = (f32x4){0.f, 0.f, 0.f, 0.f};

  // staging geometry: 8 regions of 16 rows; wave wid stages regions 2w, 2w+1
  const int r0 = wid * 2, r1 = wid * 2 + 1;
  const int sr0 = r0 * 16 + (lane >> 2), sr1 = r1 * 16 + (lane >> 2);
  const int seg = (lane & 3) * 8;
  const int fr = lane & 15, kg = lane >> 4;

  for (int k0 = 0; k0 < K; k0 += 32) {
    __syncthreads();
    gload_lds16(X + (size_t)(bm + sr0) * K + k0 + seg, As + r0 * 512);
    gload_lds16(X + (size_t)(bm + sr1) * K + k0 + seg, As + r1 * 512);
    gload_lds16(Wt + (size_t)(bn + sr0) * K + k0 + seg, Bs + r0 * 512);
    gload_lds16(Wt + (size_t)(bn + sr1) * K + k0 + seg, Bs + r1 * 512);
    __syncthreads();
    bf16x8 a[4], b[4];
#pragma unroll
    for (int m = 0; m < 4; ++m)
      a[m] = *(const bf16x8*)&As[(wr * 64 + m * 16 + fr) * 32 + kg * 8];
#pragma unroll
    for (int n = 0; n < 4; ++n)
      b[n] = *(const bf16x8*)&Bs[(wc * 64 + n * 16 + fr) * 32 + kg * 8];
#pragma unroll
    for (int m = 0; m < 4; ++m)
#pragma unroll
      for (int n = 0; n < 4; ++n)
        acc[m][n] = __builtin_amdgcn_mfma_f32_16x16x32_bf16(a[m], b[n], acc[m][n], 0, 0, 0);
  }

  const int fq = lane >> 4;
#pragma unroll
  for (int m = 0; m < 4; ++m) {
    const int gr0 = bm + wr * 64 + m * 16 + fq * 4;
#pragma unroll
    for (int n = 0; n < 4; ++n) {
      const int gc = bn + wc * 64 + n * 16 + fr;
      const float bv = bias[gc];
#pragma unroll
      for (int r = 0; r < 4; ++r) {
        const int row = gr0 + r;
        float v = acc[m][n][r] + bv;
        if constexpr (MODE == 0) {
          ((unsigned short*)Yv)[(size_t)row * N + gc] = f2b(v);
        } else if constexpr (MODE == 1) {
          ((float*)Yv)[(size_t)row * N + gc] = v + resid[(size_t)row * N + gc];
        } else if constexpr (MODE == 2) {
          v = 0.5f * v * (1.f + erff(v * 0.70710678118654752f));
          ((unsigned short*)Yv)[(size_t)row * N + gc] = f2b(v);
        } else {
          v += resid[(size_t)row * N + gc];
          const int bb = row >> 10, s = row & (S_ - 1);
          ((float*)Yv)[((size_t)(s * B_ + bb)) * D_ + gc] = v;
        }
      }
    }
  }
}

// ---------------- Fused relative attention (f32 math, bf16 I/O) ----------------
// grid: (S/8, B*H); 256 threads = 4 waves, wave w owns q-rows 2w, 2w+1.
__global__ __launch_bounds__(256) void attn_kernel(
    const unsigned short* __restrict__ Q, const unsigned short* __restrict__ Kb,
    const unsigned short* __restrict__ Vb, const float* __restrict__ relk,
    const float* __restrict__ relv, unsigned short* __restrict__ Wctx) {
  __shared__ float sc[8][S_];        // 32 KB
  __shared__ float tile[64 * 64];    // 16 KB, XOR-swizzled 4-float groups
  __shared__ float qs[8][68];        // 2.2 KB
  __shared__ float qrel[8][102];     // 3.3 KB
  __shared__ float pr[8][102];       // 3.3 KB

  const int q0 = blockIdx.x * 8;
  const int bh = blockIdx.y, b = bh >> 4, h = bh & 15;
  const int tid = threadIdx.x, w = tid >> 6, lane = tid & 63;
  const size_t base = ((size_t)b * S_) * D_ + h * HD_;

  // stage Q rows (bf16 -> f32)
  for (int idx = tid; idx < 8 * HD_; idx += 256) {
    const int i = idx >> 6, d = idx & 63;
    qs[i][d] = b2f(Q[base + (size_t)(q0 + i) * D_ + d]);
  }
  __syncthreads();

  // qrel[i][r] = qs[i] . relk[r]
  for (int p = w; p < 8 * NREL; p += 4) {
    const int i = p / NREL, r = p - i * NREL;
    float v = qs[i][lane] * relk[r * HD_ + lane];
    v = wave_red_sum(v);
    if (lane == 0) qrel[i][r] = v;
  }
  __syncthreads();

  const int i0 = w * 2;
  const int qi0 = q0 + i0, qi1 = qi0 + 1;

  // ---- scores ----
  for (int kt = 0; kt < 16; ++kt) {
    const int k0 = kt * 64;
    __syncthreads();
    {  // stage 64x64 K-tile, bf16->f32, swizzled: 16 elems/thread
      const int row = tid >> 2, g0 = (tid & 3) * 4;           // 4 groups of 4 floats
      const size_t gsrc = base + (size_t)(k0 + row) * D_ + g0 * 4;
      u16x8 h0 = *(const u16x8*)(Kb + gsrc);
      u16x8 h1 = *(const u16x8*)(Kb + gsrc + 8);
      float f[16];
#pragma unroll
      for (int e = 0; e < 8; ++e) { f[e] = b2f(h0[e]); f[8 + e] = b2f(h1[e]); }
#pragma unroll
      for (int j = 0; j < 4; ++j) {
        const int pg = (g0 + j) ^ (row & 15);
        float4 t = make_float4(f[j * 4], f[j * 4 + 1], f[j * 4 + 2], f[j * 4 + 3]);
        *(float4*)&tile[row * 64 + pg * 4] = t;
      }
    }
    __syncthreads();
    float d0 = 0.f, d1 = 0.f;
#pragma unroll
    for (int g = 0; g < 16; ++g) {
      const int pg = g ^ (lane & 15);
      float4 tv = *(const float4*)&tile[lane * 64 + pg * 4];
      float4 qa = *(const float4*)&qs[i0][g * 4];
      float4 qb = *(const float4*)&qs[i0 + 1][g * 4];
      d0 = fmaf(tv.x, qa.x, fmaf(tv.y, qa.y, fmaf(tv.z, qa.z, fmaf(tv.w, qa.w, d0))));
      d1 = fmaf(tv.x, qb.x, fmaf(tv.y, qb.y, fmaf(tv.z, qb.z, fmaf(tv.w, qb.w, d1))));
    }
    const int k = k0 + lane;
    const int r0i = min(max(k - qi0, -50), 50) + 50;
    const int r1i = min(max(k - qi1, -50), 50) + 50;
    sc[i0][k]     = (d0 + qrel[i0][r0i]) * 0.125f;
    sc[i0 + 1][k] = (d1 + qrel[i0 + 1][r1i]) * 0.125f;
  }

  // ---- softmax (wave-local rows) ----
#pragma unroll
  for (int ii = 0; ii < 2; ++ii) {
    const int i = i0 + ii;
    float m = -1e30f;
#pragma unroll
    for (int j = 0; j < 16; ++j) m = fmaxf(m, sc[i][lane + j * 64]);
    m = wave_red_max(m);
    float sum = 0.f;
#pragma unroll
    for (int j = 0; j < 16; ++j) {
      const float e = __expf(sc[i][lane + j * 64] - m);
      sc[i][lane + j * 64] = e;
      sum += e;
    }
    sum = wave_red_sum(sum);
    const float inv = 1.f / sum;
#pragma unroll
    for (int j = 0; j < 16; ++j) sc[i][lane + j * 64] *= inv;
  }

  // ---- pr[i][r]: collapse p over clipped relative distance ----
#pragma unroll
  for (int ii = 0; ii < 2; ++ii) {
    const int i = i0 + ii, qi = q0 + i;
    for (int r = lane; r < NREL; r += 64) {
      if (r != 0 && r != 100) {
        const int k = qi + r - 50;
        pr[i][r] = (k >= 0 && k < S_) ? sc[i][k] : 0.f;
      }
    }
    float sL = 0.f;
    for (int k = lane; k <= qi - 50; k += 64) sL += sc[i][k];
    sL = wave_red_sum(sL);
    float sR = 0.f;
    for (int k = qi + 50 + lane; k < S_; k += 64) sR += sc[i][k];
    sR = wave_red_sum(sR);
    if (lane == 0) { pr[i][0] = sL; pr[i][100] = sR; }
  }

  // ---- PV: acc[d] = sum_k p[k] * V[k,d], V staged in LDS per tile ----
  float a0 = 0.f, a1 = 0.f;
  for (int kt = 0; kt < 16; ++kt) {
    const int k0 = kt * 64;
    __syncthreads();
    {  // stage V-tile (same swizzle)
      const int row = tid >> 2, g0 = (tid & 3) * 4;
      const size_t gsrc = base + (size_t)(k0 + row) * D_ + g0 * 4;
      u16x8 h0 = *(const u16x8*)(Vb + gsrc);
      u16x8 h1 = *(const u16x8*)(Vb + gsrc + 8);
      float f[16];
#pragma unroll
      for (int e = 0; e < 8; ++e) { f[e] = b2f(h0[e]); f[8 + e] = b2f(h1[e]); }
#pragma unroll
      for (int j = 0; j < 4; ++j) {
        const int pg = (g0 + j) ^ (row & 15);
        float4 t = make_float4(f[j * 4], f[j * 4 + 1], f[j * 4 + 2], f[j * 4 + 3]);
        *(float4*)&tile[row * 64 + pg * 4] = t;
      }
    }
    __syncthreads();
    const float* p0 = &sc[i0][k0];
    const float* p1 = &sc[i0 + 1][k0];
#pragma unroll 4
    for (int kk = 0; kk < 64; kk += 4) {
      float4 pv0 = *(const float4*)(p0 + kk);
      float4 pv1 = *(const float4*)(p1 + kk);
      const float p0e[4] = {pv0.x, pv0.y, pv0.z, pv0.w};
      const float p1e[4] = {pv1.x, pv1.y, pv1.z, pv1.w};
#pragma unroll
      for (int e = 0; e < 4; ++e) {
        const int k = kk + e;
        const float v = tile[k * 64 + (((lane >> 2) ^ (k & 15)) << 2) + (lane & 3)];
        a0 = fmaf(p0e[e], v, a0);
        a1 = fmaf(p1e[e], v, a1);
      }
    }
  }

  // ---- w2 = pr . relv, add, store bf16 ----
  float w20 = 0.f, w21 = 0.f;
  for (int r = 0; r < NREL; ++r) {
    const float rv = relv[r * HD_ + lane];
    w20 = fmaf(pr[i0][r], rv, w20);
    w21 = fmaf(pr[i0 + 1][r], rv, w21);
  }
  Wctx[base + (size_t)qi0 * D_ + lane] = f2b(a0 + w20);
  Wctx[base + (size_t)qi1 * D_ + lane] = f2b(a1 + w21);
}

// ---------------- launch ----------------
extern "C" void kernel_launch(void* const* d_in, const int* in_sizes, int n_in,
                              void* d_out, int out_size, void* d_ws, size_t ws_size,
                              hipStream_t stream) {
  (void)in_sizes; (void)n_in; (void)out_size; (void)ws_size;
  const float* x      = (const float*)d_in[0];
  const float* Wq     = (const float*)d_in[1];
  const float* bq     = (const float*)d_in[2];
  const float* Wk     = (const float*)d_in[3];
  const float* bk     = (const float*)d_in[4];
  const float* Wv     = (const float*)d_in[5];
  const float* bv     = (const float*)d_in[6];
  const float* Wo     = (const float*)d_in[7];
  const float* bo     = (const float*)d_in[8];
  const float* rel_k  = (const float*)d_in[9];
  const float* rel_v  = (const float*)d_in[10];
  const float* g_attn = (const float*)d_in[11];
  const float* g_ff   = (const float*)d_in[12];
  const float* W_in   = (const float*)d_in[13];
  const float* b_in   = (const float*)d_in[14];
  const float* W_out  = (const float*)d_in[15];
  const float* b_out  = (const float*)d_in[16];
  float* out = (float*)d_out;

  const size_t MB = 1u << 20;
  const size_t NE = (size_t)MROWS * D_;          // 4M elements
  char* Wp = (char*)d_ws;
  float*          hbF  = (float*)Wp;              // 16MB f32 [B,S,D]
  unsigned short* hbB  = (unsigned short*)(Wp + 16 * MB);   // 8MB bf16
  char*           C    = Wp + 24 * MB;            // 32MB region (qkv+wctx, later ff1)
  unsigned short* qB   = (unsigned short*)C;
  unsigned short* kB   = qB + NE;
  unsigned short* vB   = kB + NE;
  unsigned short* wB   = vB + NE;
  unsigned short* ff1B = (unsigned short*)C;      // overlays qkv+wctx (dead by then)
  unsigned short* fB   = (unsigned short*)(Wp + 56 * MB);   // 8MB bf16
  float*          h2   = (float*)(Wp + 64 * MB);  // 16MB f32
  unsigned short* wqB  = (unsigned short*)(Wp + 80 * MB);   // weights bf16: 24MB
  unsigned short* wkB  = wqB + (size_t)D_ * D_;
  unsigned short* wvB  = wkB + (size_t)D_ * D_;
  unsigned short* woB  = wvB + (size_t)D_ * D_;
  unsigned short* winB = woB + (size_t)D_ * D_;
  unsigned short* woutB= winB + (size_t)DFF_ * D_;

  // weight converts
  hipLaunchKernelGGL(cvt_kernel, dim3(1024), dim3(256), 0, stream, Wq, wqB, D_ * D_);
  hipLaunchKernelGGL(cvt_kernel, dim3(1024), dim3(256), 0, stream, Wk, wkB, D_ * D_);
  hipLaunchKernelGGL(cvt_kernel, dim3(1024), dim3(256), 0, stream, Wv, wvB, D_ * D_);
  hipLaunchKernelGGL(cvt_kernel, dim3(1024), dim3(256), 0, stream, Wo, woB, D_ * D_);
  hipLaunchKernelGGL(cvt_kernel, dim3(4096), dim3(256), 0, stream, W_in, winB, DFF_ * D_);
  hipLaunchKernelGGL(cvt_kernel, dim3(4096), dim3(256), 0, stream, W_out, woutB, DFF_ * D_);

  // 1. pre-norm + transpose -> hbB (bf16) + hbF (f32)
  hipLaunchKernelGGL((rmsnorm_kernel<true, true>), dim3(MROWS), dim3(256), 0, stream,
                     x, g_attn, hbB, hbF);
  // 2. QKV projections (bf16 MFMA)
  dim3 g1(MROWS / 128, D_ / 128);
  hipLaunchKernelGGL((gemm_bf16<0>), g1, dim3(256), 0, stream, hbB, wqB, bq, nullptr, qB, D_, D_);
  hipLaunchKernelGGL((gemm_bf16<0>), g1, dim3(256), 0, stream, hbB, wkB, bk, nullptr, kB, D_, D_);
  hipLaunchKernelGGL((gemm_bf16<0>), g1, dim3(256), 0, stream, hbB, wvB, bv, nullptr, vB, D_, D_);
  // 3. fused relative attention
  hipLaunchKernelGGL(attn_kernel, dim3(S_ / 8, B_ * H_), dim3(256), 0, stream,
                     qB, kB, vB, rel_k, rel_v, wB);
  // 4. O-proj + residual -> h2 (f32)
  hipLaunchKernelGGL((gemm_bf16<1>), g1, dim3(256), 0, stream, wB, woB, bo, hbF, h2, D_, D_);
  // 5. second rmsnorm -> fB (bf16)
  hipLaunchKernelGGL((rmsnorm_kernel<false, false>), dim3(MROWS), dim3(256), 0, stream,
                     h2, g_ff, fB, nullptr);
  // 6. FFN up + gelu -> ff1B (bf16)
  dim3 g2(MROWS / 128, DFF_ / 128);
  hipLaunchKernelGGL((gemm_bf16<2>), g2, dim3(256), 0, stream, fB, winB, b_in, nullptr, ff1B, DFF_, D_);
  // 7. FFN down + residual + transposed store -> out (f32)
  hipLaunchKernelGGL((gemm_bf16<3>), g1, dim3(256), 0, stream, ff1B, woutB, b_out, h2, out, D_, DFF_);
}

// Round 4
// 633.991 us; speedup vs baseline: 7.4038x; 3.8596x over previous
//
#include <hip/hip_runtime.h>
#include <hip/hip_bf16.h>

#define S_   1024
#define B_   4
#define D_   1024
#define H_   16
#define HD_  64
#define DFF_ 4096
#define NREL 101
#define MROWS (S_*B_)

typedef __attribute__((ext_vector_type(8))) short bf16x8;
typedef __attribute__((ext_vector_type(4))) float f32x4;

__device__ __forceinline__ float b2f(unsigned short u) {
  unsigned int v = ((unsigned int)u) << 16;
  return __builtin_bit_cast(float, v);
}
__device__ __forceinline__ unsigned short f2b(float f) {
  unsigned int v = __builtin_bit_cast(unsigned int, f);
  v += 0x7fffu + ((v >> 16) & 1u);
  return (unsigned short)(v >> 16);
}

__device__ __forceinline__ float wave_red_sum(float v) {
#pragma unroll
  for (int o = 32; o; o >>= 1) v += __shfl_xor(v, o, 64);
  return v;
}
__device__ __forceinline__ float wave_red_max(float v) {
#pragma unroll
  for (int o = 32; o; o >>= 1) v = fmaxf(v, __shfl_xor(v, o, 64));
  return v;
}

__device__ __forceinline__ void gload_lds16(const void* g, void* l) {
  __builtin_amdgcn_global_load_lds(
      (const __attribute__((address_space(1))) void*)g,
      (__attribute__((address_space(3))) void*)l, 16, 0, 0);
}

// swizzled dword index within a 1024-float score row: chunk(16B) ^ (q&7)
__device__ __forceinline__ int swza(int k, int q) {
  return (((k >> 2) ^ (q & 7)) << 2) | (k & 3);
}

// ---------------- f32 -> bf16 convert (with zero pad to n_tot) ----------------
__global__ __launch_bounds__(256) void cvt_kernel(
    const float* __restrict__ s, unsigned short* __restrict__ d, int n_src, int n_tot) {
  int i = (blockIdx.x * 256 + threadIdx.x) * 4;
  if (i >= n_tot) return;
  if (i + 4 <= n_src) {
    float4 v = *(const float4*)(s + i);
    ushort4 o; o.x = f2b(v.x); o.y = f2b(v.y); o.z = f2b(v.z); o.w = f2b(v.w);
    *(ushort4*)(d + i) = o;
  } else {
#pragma unroll
    for (int e = 0; e < 4; ++e)
      if (i + e < n_tot) d[i + e] = (i + e < n_src) ? f2b(s[i + e]) : (unsigned short)0;
  }
}

// ---------------- RMSNorm: f32 in -> bf16 out (+ optional f32 out) ----------------
template<bool TO_BSD, bool WF32>
__global__ __launch_bounds__(256) void rmsnorm_kernel(
    const float* __restrict__ x, const float* __restrict__ g,
    unsigned short* __restrict__ yb, float* __restrict__ yf) {
  const int row = blockIdx.x;
  int orow = row;
  if (TO_BSD) { int s = row >> 2, b = row & 3; orow = b * S_ + s; }  // row = s*B+b
  const float4 v = *(const float4*)(x + (size_t)row * D_ + threadIdx.x * 4);
  float ss = v.x * v.x + v.y * v.y + v.z * v.z + v.w * v.w;
  ss = wave_red_sum(ss);
  __shared__ float red[4];
  if ((threadIdx.x & 63) == 0) red[threadIdx.x >> 6] = ss;
  __syncthreads();
  const float tot = red[0] + red[1] + red[2] + red[3];
  const float inv = 1.f / (sqrtf(tot) * (1.f / 32.f) + 1e-8f);
  const float4 gg = *(const float4*)(g + threadIdx.x * 4);
  const float o0 = gg.x * v.x * inv, o1 = gg.y * v.y * inv;
  const float o2 = gg.z * v.z * inv, o3 = gg.w * v.w * inv;
  const size_t ob = (size_t)orow * D_ + threadIdx.x * 4;
  ushort4 ub; ub.x = f2b(o0); ub.y = f2b(o1); ub.z = f2b(o2); ub.w = f2b(o3);
  *(ushort4*)(yb + ob) = ub;
  if (WF32) { float4 of = make_float4(o0, o1, o2, o3); *(float4*)(yf + ob) = of; }
}

// ---------------- bf16 MFMA GEMM (m97 structure): Y[M,N] = X[M,K] * W[N,K]^T + bias ----------------
// MODE 0: bf16 out = acc + bias                       (Q,K proj)
// MODE 1: f32  out = acc + bias + resid               (O-proj -> h2)
// MODE 2: bf16 out = gelu(acc + bias)                 (FFN up)
// MODE 3: f32  out[(s*B+b)*D+col] = acc+bias+resid    (final, transposed store)
// MODE 4: bf16 out transposed per-head: vT[(b*1024+col)*1024 + s]   (V proj)
template<int MODE>
__global__ __launch_bounds__(256) void gemm_bf16(
    const unsigned short* __restrict__ X, const unsigned short* __restrict__ Wt,
    const float* __restrict__ bias, const float* __restrict__ resid,
    void* __restrict__ Yv, int N, int K) {
  __shared__ __align__(16) unsigned short As[128 * 32];
  __shared__ __align__(16) unsigned short Bs[128 * 32];
  const int tid = threadIdx.x;
  const int wid = tid >> 6, lane = tid & 63;
  const int bm = blockIdx.x * 128, bn = blockIdx.y * 128;
  const int wr = wid >> 1, wc = wid & 1;

  f32x4 acc[4][4];
#pragma unroll
  for (int m = 0; m < 4; ++m)
#pragma unroll
    for (int n = 0; n < 4; ++n) acc[m][n] = (f32x4){0.f, 0.f, 0.f, 0.f};

  const int r0 = wid * 2, r1 = wid * 2 + 1;
  const int sr0 = r0 * 16 + (lane >> 2), sr1 = r1 * 16 + (lane >> 2);
  const int seg = (lane & 3) * 8;
  const int fr = lane & 15, kg = lane >> 4;

  for (int k0 = 0; k0 < K; k0 += 32) {
    __syncthreads();
    gload_lds16(X + (size_t)(bm + sr0) * K + k0 + seg, As + r0 * 512);
    gload_lds16(X + (size_t)(bm + sr1) * K + k0 + seg, As + r1 * 512);
    gload_lds16(Wt + (size_t)(bn + sr0) * K + k0 + seg, Bs + r0 * 512);
    gload_lds16(Wt + (size_t)(bn + sr1) * K + k0 + seg, Bs + r1 * 512);
    __syncthreads();
    bf16x8 a[4], b[4];
#pragma unroll
    for (int m = 0; m < 4; ++m)
      a[m] = *(const bf16x8*)&As[(wr * 64 + m * 16 + fr) * 32 + kg * 8];
#pragma unroll
    for (int n = 0; n < 4; ++n)
      b[n] = *(const bf16x8*)&Bs[(wc * 64 + n * 16 + fr) * 32 + kg * 8];
#pragma unroll
    for (int m = 0; m < 4; ++m)
#pragma unroll
      for (int n = 0; n < 4; ++n)
        acc[m][n] = __builtin_amdgcn_mfma_f32_16x16x32_bf16(a[m], b[n], acc[m][n], 0, 0, 0);
  }

  const int fq = lane >> 4;
#pragma unroll
  for (int m = 0; m < 4; ++m) {
    const int gr0 = bm + wr * 64 + m * 16 + fq * 4;
#pragma unroll
    for (int n = 0; n < 4; ++n) {
      const int gc = bn + wc * 64 + n * 16 + fr;
      const float bv = bias[gc];
      if constexpr (MODE == 4) {
        ushort4 st;
        st.x = f2b(acc[m][n][0] + bv); st.y = f2b(acc[m][n][1] + bv);
        st.z = f2b(acc[m][n][2] + bv); st.w = f2b(acc[m][n][3] + bv);
        const int bb = gr0 >> 10, s = gr0 & (S_ - 1);
        *(ushort4*)((unsigned short*)Yv + ((size_t)(bb * 1024 + gc)) * 1024 + s) = st;
      } else {
#pragma unroll
        for (int r = 0; r < 4; ++r) {
          const int row = gr0 + r;
          float v = acc[m][n][r] + bv;
          if constexpr (MODE == 0) {
            ((unsigned short*)Yv)[(size_t)row * N + gc] = f2b(v);
          } else if constexpr (MODE == 1) {
            ((float*)Yv)[(size_t)row * N + gc] = v + resid[(size_t)row * N + gc];
          } else if constexpr (MODE == 2) {
            v = 0.5f * v * (1.f + erff(v * 0.70710678118654752f));
            ((unsigned short*)Yv)[(size_t)row * N + gc] = f2b(v);
          } else {
            v += resid[(size_t)row * N + gc];
            const int bb = row >> 10, s = row & (S_ - 1);
            ((float*)Yv)[((size_t)(s * B_ + bb)) * D_ + gc] = v;
          }
        }
      }
    }
  }
}

// ---------------- MFMA relative attention ----------------
// grid: (S/16, B*H), 256 threads = 4 waves. Block: 16 q-rows of one (b,h).
// Wave w: QK^T cols {j*64 + w*16 + 0..15}, PV d-tile w*16..w*16+15 (O^T orientation).
__global__ __launch_bounds__(256) void attn_mfma(
    const unsigned short* __restrict__ Q, const unsigned short* __restrict__ Kb,
    const unsigned short* __restrict__ vT, const unsigned short* __restrict__ relkB,
    const float* __restrict__ relv, unsigned short* __restrict__ Wctx) {
  __shared__ float sc[16 * 1024];      // 64KB, swizzled chunks (chunk ^ (q&7))
  __shared__ float qrelp[16 * 113];    // 7.2KB: qrel bias, reused as pr bins
  __shared__ float rsum[16];

  const int q0 = blockIdx.x * 16;
  const int bh = blockIdx.y, b = bh >> 4, h = bh & 15;
  const int tid = threadIdx.x, w = tid >> 6, lane = tid & 63;
  const int fr = lane & 15, kg = lane >> 4;
  const size_t base = ((size_t)b * S_) * D_ + h * HD_;

  // Q A-fragments (held in registers for whole kernel)
  bf16x8 qa0 = *(const bf16x8*)(Q + base + (size_t)(q0 + fr) * D_ + kg * 8);
  bf16x8 qa1 = *(const bf16x8*)(Q + base + (size_t)(q0 + fr) * D_ + 32 + kg * 8);

  // ---- qrel[q][r] = Q-row q . rel_k[r], via MFMA (7 col-tiles over padded 112) ----
  for (int rt = w; rt < 7; rt += 4) {
    f32x4 c = (f32x4){0.f, 0.f, 0.f, 0.f};
    bf16x8 b0 = *(const bf16x8*)(relkB + (rt * 16 + fr) * 64 + kg * 8);
    bf16x8 b1 = *(const bf16x8*)(relkB + (rt * 16 + fr) * 64 + 32 + kg * 8);
    c = __builtin_amdgcn_mfma_f32_16x16x32_bf16(qa0, b0, c, 0, 0, 0);
    c = __builtin_amdgcn_mfma_f32_16x16x32_bf16(qa1, b1, c, 0, 0, 0);
#pragma unroll
    for (int rr = 0; rr < 4; ++rr)
      qrelp[(kg * 4 + rr) * 113 + rt * 16 + fr] = c[rr];
  }
  __syncthreads();

  // ---- QK^T: 16 j-steps, each 16x16 out tile (cols = k), immediate biased write ----
#pragma unroll 4
  for (int j = 0; j < 16; ++j) {
    const int krow = j * 64 + w * 16 + fr;
    const unsigned short* kp = Kb + base + (size_t)krow * D_ + kg * 8;
    bf16x8 kf0 = *(const bf16x8*)(kp);
    bf16x8 kf1 = *(const bf16x8*)(kp + 32);
    f32x4 c = (f32x4){0.f, 0.f, 0.f, 0.f};
    c = __builtin_amdgcn_mfma_f32_16x16x32_bf16(qa0, kf0, c, 0, 0, 0);
    c = __builtin_amdgcn_mfma_f32_16x16x32_bf16(qa1, kf1, c, 0, 0, 0);
    const int k = krow;   // col index of this lane
#pragma unroll
    for (int rr = 0; rr < 4; ++rr) {
      const int q = kg * 4 + rr;
      const int ridx = min(max(k - (q0 + q), -50), 50) + 50;
      sc[q * 1024 + swza(k, q)] = (c[rr] + qrelp[q * 113 + ridx]) * 0.125f;
    }
  }
  __syncthreads();

  // ---- softmax (unnormalized exp kept) + pr bins; wave w owns rows 4w..4w+3 ----
#pragma unroll
  for (int rq = 0; rq < 4; ++rq) {
    const int q = w * 4 + rq;
    float* row = sc + q * 1024;
    float m = -1e30f;
#pragma unroll
    for (int it = 0; it < 16; ++it) m = fmaxf(m, row[lane + it * 64]);
    m = wave_red_max(m);
    float sum = 0.f;
#pragma unroll
    for (int it = 0; it < 16; ++it) {
      const float e = __expf(row[lane + it * 64] - m);
      row[lane + it * 64] = e;
      sum += e;
    }
    sum = wave_red_sum(sum);
    if (lane == 0) rsum[q] = sum;
    // pr bins (unnormalized)
    const int qi = q0 + q;
    float* prq = qrelp + q * 113;
    for (int r = lane; r < NREL; r += 64) {
      if (r != 0 && r != 100) {
        const int kk = qi + r - 50;
        prq[r] = (kk >= 0 && kk < S_) ? row[swza(kk, q)] : 0.f;
      }
    }
    float sL = 0.f;
    for (int kk = lane; kk <= qi - 50; kk += 64) sL += row[swza(kk, q)];
    sL = wave_red_sum(sL);
    float sR = 0.f;
    for (int kk = qi + 50 + lane; kk < S_; kk += 64) sR += row[swza(kk, q)];
    sR = wave_red_sum(sR);
    if (lane == 0) { prq[0] = sL; prq[100] = sR; }
  }
  __syncthreads();

  // ---- PV (O^T orientation): A = V^T rows (d), B = P rows (q) ----
  const int dtile = w * 16;
  const size_t vtb = ((size_t)(b * 1024 + h * 64 + dtile + fr)) * 1024;
  const float rinv = 1.f / rsum[fr];
  f32x4 o = (f32x4){0.f, 0.f, 0.f, 0.f};
#pragma unroll 4
  for (int ks = 0; ks < 32; ++ks) {
    bf16x8 va = *(const bf16x8*)(vT + vtb + ks * 32 + kg * 8);
    const int c0 = ((ks * 8 + kg * 2) ^ (fr & 7)) << 2;
    const int c1 = ((ks * 8 + kg * 2 + 1) ^ (fr & 7)) << 2;
    const float4 f0 = *(const float4*)&sc[fr * 1024 + c0];
    const float4 f1 = *(const float4*)&sc[fr * 1024 + c1];
    union { bf16x8 v; unsigned short u[8]; } pb;
    pb.u[0] = f2b(f0.x * rinv); pb.u[1] = f2b(f0.y * rinv);
    pb.u[2] = f2b(f0.z * rinv); pb.u[3] = f2b(f0.w * rinv);
    pb.u[4] = f2b(f1.x * rinv); pb.u[5] = f2b(f1.y * rinv);
    pb.u[6] = f2b(f1.z * rinv); pb.u[7] = f2b(f1.w * rinv);
    o = __builtin_amdgcn_mfma_f32_16x16x32_bf16(va, pb.v, o, 0, 0, 0);
  }

  // ---- w2 = pr . relv (deferred normalization), add, packed store ----
  const int q = fr;                    // col of O^T
  const int dl = kg * 4;               // row base within wave's d-tile
  f32x4 w2 = (f32x4){0.f, 0.f, 0.f, 0.f};
  const float* prq = qrelp + q * 113;
  for (int r = 0; r < NREL; ++r) {
    const float p = prq[r];
    const float4 rv = *(const float4*)&relv[r * 64 + dtile + dl];
    w2[0] = fmaf(p, rv.x, w2[0]); w2[1] = fmaf(p, rv.y, w2[1]);
    w2[2] = fmaf(p, rv.z, w2[2]); w2[3] = fmaf(p, rv.w, w2[3]);
  }
  ushort4 st;
  st.x = f2b(o[0] + w2[0] * rinv);
  st.y = f2b(o[1] + w2[1] * rinv);
  st.z = f2b(o[2] + w2[2] * rinv);
  st.w = f2b(o[3] + w2[3] * rinv);
  *(ushort4*)(Wctx + base + (size_t)(q0 + q) * D_ + dtile + dl) = st;
}

// ---------------- launch ----------------
extern "C" void kernel_launch(void* const* d_in, const int* in_sizes, int n_in,
                              void* d_out, int out_size, void* d_ws, size_t ws_size,
                              hipStream_t stream) {
  (void)in_sizes; (void)n_in; (void)out_size; (void)ws_size;
  const float* x      = (const float*)d_in[0];
  const float* Wq     = (const float*)d_in[1];
  const float* bq     = (const float*)d_in[2];
  const float* Wk     = (const float*)d_in[3];
  const float* bk     = (const float*)d_in[4];
  const float* Wv     = (const float*)d_in[5];
  const float* bv     = (const float*)d_in[6];
  const float* Wo     = (const float*)d_in[7];
  const float* bo     = (const float*)d_in[8];
  const float* rel_k  = (const float*)d_in[9];
  const float* rel_v  = (const float*)d_in[10];
  const float* g_attn = (const float*)d_in[11];
  const float* g_ff   = (const float*)d_in[12];
  const float* W_in   = (const float*)d_in[13];
  const float* b_in   = (const float*)d_in[14];
  const float* W_out  = (const float*)d_in[15];
  const float* b_out  = (const float*)d_in[16];
  float* out = (float*)d_out;

  const size_t MB = 1u << 20;
  const size_t NE = (size_t)MROWS * D_;     // 4M elements
  char* Wp = (char*)d_ws;
  float*          hbF  = (float*)Wp;                         // 16MB f32 [B,S,D]
  unsigned short* hbB  = (unsigned short*)(Wp + 16 * MB);    // 8MB bf16
  char*           C    = Wp + 24 * MB;                       // 32MB (qkv+wctx | ff1)
  unsigned short* qB   = (unsigned short*)C;
  unsigned short* kB   = qB + NE;
  unsigned short* vT   = kB + NE;                            // [b*1024+h*64+d][s]
  unsigned short* wB   = vT + NE;
  unsigned short* ff1B = (unsigned short*)C;                 // overlays (dead by then)
  unsigned short* fB   = (unsigned short*)(Wp + 56 * MB);    // 8MB bf16
  float*          h2   = (float*)(Wp + 64 * MB);             // 16MB f32
  unsigned short* wqB  = (unsigned short*)(Wp + 80 * MB);    // weights bf16: 24MB
  unsigned short* wkB  = wqB + (size_t)D_ * D_;
  unsigned short* wvB  = wkB + (size_t)D_ * D_;
  unsigned short* woB  = wvB + (size_t)D_ * D_;
  unsigned short* winB = woB + (size_t)D_ * D_;
  unsigned short* woutB= winB + (size_t)DFF_ * D_;
  unsigned short* relkB= woutB + (size_t)DFF_ * D_;          // 112x64 bf16 (zero-padded)

  // weight converts
  hipLaunchKernelGGL(cvt_kernel, dim3(1024), dim3(256), 0, stream, Wq, wqB, D_*D_, D_*D_);
  hipLaunchKernelGGL(cvt_kernel, dim3(1024), dim3(256), 0, stream, Wk, wkB, D_*D_, D_*D_);
  hipLaunchKernelGGL(cvt_kernel, dim3(1024), dim3(256), 0, stream, Wv, wvB, D_*D_, D_*D_);
  hipLaunchKernelGGL(cvt_kernel, dim3(1024), dim3(256), 0, stream, Wo, woB, D_*D_, D_*D_);
  hipLaunchKernelGGL(cvt_kernel, dim3(4096), dim3(256), 0, stream, W_in,  winB,  DFF_*D_, DFF_*D_);
  hipLaunchKernelGGL(cvt_kernel, dim3(4096), dim3(256), 0, stream, W_out, woutB, DFF_*D_, DFF_*D_);
  hipLaunchKernelGGL(cvt_kernel, dim3(7), dim3(256), 0, stream, rel_k, relkB, NREL*HD_, 112*HD_);

  // 1. pre-norm + transpose -> hbB (bf16) + hbF (f32)
  hipLaunchKernelGGL((rmsnorm_kernel<true, true>), dim3(MROWS), dim3(256), 0, stream,
                     x, g_attn, hbB, hbF);
  // 2. QKV projections (V stored transposed per-head)
  dim3 g1(MROWS / 128, D_ / 128);
  hipLaunchKernelGGL((gemm_bf16<0>), g1, dim3(256), 0, stream, hbB, wqB, bq, nullptr, qB, D_, D_);
  hipLaunchKernelGGL((gemm_bf16<0>), g1, dim3(256), 0, stream, hbB, wkB, bk, nullptr, kB, D_, D_);
  hipLaunchKernelGGL((gemm_bf16<4>), g1, dim3(256), 0, stream, hbB, wvB, bv, nullptr, vT, D_, D_);
  // 3. MFMA relative attention
  hipLaunchKernelGGL(attn_mfma, dim3(S_ / 16, B_ * H_), dim3(256), 0, stream,
                     qB, kB, vT, relkB, rel_v, wB);
  // 4. O-proj + residual -> h2 (f32)
  hipLaunchKernelGGL((gemm_bf16<1>), g1, dim3(256), 0, stream, wB, woB, bo, hbF, h2, D_, D_);
  // 5. second rmsnorm -> fB (bf16)
  hipLaunchKernelGGL((rmsnorm_kernel<false, false>), dim3(MROWS), dim3(256), 0, stream,
                     h2, g_ff, fB, nullptr);
  // 6. FFN up + gelu -> ff1B (bf16)
  dim3 g2(MROWS / 128, DFF_ / 128);
  hipLaunchKernelGGL((gemm_bf16<2>), g2, dim3(256), 0, stream, fB, winB, b_in, nullptr, ff1B, DFF_, D_);
  // 7. FFN down + residual + transposed store -> out (f32)
  hipLaunchKernelGGL((gemm_bf16<3>), g1, dim3(256), 0, stream, ff1B, woutB, b_out, h2, out, D_, DFF_);
}

// Round 5
// 592.986 us; speedup vs baseline: 7.9158x; 1.0692x over previous
//
#include <hip/hip_runtime.h>
#include <hip/hip_bf16.h>

#define S_   1024
#define B_   4
#define D_   1024
#define H_   16
#define HD_  64
#define DFF_ 4096
#define NREL 101
#define MROWS (S_*B_)

typedef __attribute__((ext_vector_type(8))) short bf16x8;
typedef __attribute__((ext_vector_type(4))) float f32x4;

__device__ __forceinline__ float b2f(unsigned short u) {
  unsigned int v = ((unsigned int)u) << 16;
  return __builtin_bit_cast(float, v);
}
__device__ __forceinline__ unsigned short f2b(float f) {
  unsigned int v = __builtin_bit_cast(unsigned int, f);
  v += 0x7fffu + ((v >> 16) & 1u);
  return (unsigned short)(v >> 16);
}

__device__ __forceinline__ float wave_red_sum(float v) {
#pragma unroll
  for (int o = 32; o; o >>= 1) v += __shfl_xor(v, o, 64);
  return v;
}
__device__ __forceinline__ float wave_red_max(float v) {
#pragma unroll
  for (int o = 32; o; o >>= 1) v = fmaxf(v, __shfl_xor(v, o, 64));
  return v;
}

__device__ __forceinline__ void gload_lds16(const void* g, void* l) {
  __builtin_amdgcn_global_load_lds(
      (const __attribute__((address_space(1))) void*)g,
      (__attribute__((address_space(3))) void*)l, 16, 0, 0);
}

// swizzled dword index within a 1024-float score row: 16B chunk ^ (q&7)
__device__ __forceinline__ int swza(int k, int q) {
  return (((k >> 2) ^ (q & 7)) << 2) | (k & 3);
}

// ---------------- one-shot weight conversion (all weights, 1 launch) ----------------
__device__ __forceinline__ void cvt4(const float* s, unsigned short* d, int idx) {
  float4 v = *(const float4*)(s + idx);
  ushort4 o; o.x = f2b(v.x); o.y = f2b(v.y); o.z = f2b(v.z); o.w = f2b(v.w);
  *(ushort4*)(d + idx) = o;
}
__global__ __launch_bounds__(256) void cvt_all(
    const float* __restrict__ Wq, const float* __restrict__ Wk, const float* __restrict__ Wv,
    const float* __restrict__ Wo, const float* __restrict__ W_in, const float* __restrict__ W_out,
    const float* __restrict__ relk,
    unsigned short* __restrict__ wqkvB, unsigned short* __restrict__ woB,
    unsigned short* __restrict__ winB, unsigned short* __restrict__ woutB,
    unsigned short* __restrict__ relkB) {
  int i = (blockIdx.x * 256 + threadIdx.x) * 4;
  const int M1 = 1048576;
  if (i < M1) { cvt4(Wq, wqkvB, i); return; }
  i -= M1;
  if (i < M1) { cvt4(Wk, wqkvB + M1, i); return; }
  i -= M1;
  if (i < M1) { cvt4(Wv, wqkvB + 2 * M1, i); return; }
  i -= M1;
  if (i < M1) { cvt4(Wo, woB, i); return; }
  i -= M1;
  if (i < 4 * M1) { cvt4(W_in, winB, i); return; }
  i -= 4 * M1;
  if (i < 4 * M1) { cvt4(W_out, woutB, i); return; }
  i -= 4 * M1;
  if (i < 7168) {
    if (i < 6464) cvt4(relk, relkB, i);
    else { ushort4 z = {0, 0, 0, 0}; *(ushort4*)(relkB + i) = z; }
  }
}

// ---------------- RMSNorm: f32 in -> bf16 out (+ optional f32 out) ----------------
template<bool TO_BSD, bool WF32>
__global__ __launch_bounds__(256) void rmsnorm_kernel(
    const float* __restrict__ x, const float* __restrict__ g,
    unsigned short* __restrict__ yb, float* __restrict__ yf) {
  const int row = blockIdx.x;
  int orow = row;
  if (TO_BSD) { int s = row >> 2, b = row & 3; orow = b * S_ + s; }  // row = s*B+b
  const float4 v = *(const float4*)(x + (size_t)row * D_ + threadIdx.x * 4);
  float ss = v.x * v.x + v.y * v.y + v.z * v.z + v.w * v.w;
  ss = wave_red_sum(ss);
  __shared__ float red[4];
  if ((threadIdx.x & 63) == 0) red[threadIdx.x >> 6] = ss;
  __syncthreads();
  const float tot = red[0] + red[1] + red[2] + red[3];
  const float inv = 1.f / (sqrtf(tot) * (1.f / 32.f) + 1e-8f);
  const float4 gg = *(const float4*)(g + threadIdx.x * 4);
  const float o0 = gg.x * v.x * inv, o1 = gg.y * v.y * inv;
  const float o2 = gg.z * v.z * inv, o3 = gg.w * v.w * inv;
  const size_t ob = (size_t)orow * D_ + threadIdx.x * 4;
  ushort4 ub; ub.x = f2b(o0); ub.y = f2b(o1); ub.z = f2b(o2); ub.w = f2b(o3);
  *(ushort4*)(yb + ob) = ub;
  if (WF32) { float4 of = make_float4(o0, o1, o2, o3); *(float4*)(yf + ob) = of; }
}

// ---------------- bf16 MFMA GEMM (m97 structure): Y[M,N] = X[M,K] * W[N,K]^T + bias ----------------
// MODE 1: f32  out = acc + bias + resid               (O-proj -> h2)
// MODE 2: bf16 out = gelu(acc + bias)                 (FFN up)
// MODE 3: f32  out[(s*B+b)*D+col] = acc+bias+resid    (final, transposed store)
// MODE 5: fused QKV: seg=gc>>10 -> Q(Yv)/K(Yv2)/V^T(Yv3); bias = concat [3072]
// MODE 6: split-K partial: f32 raw acc -> (z ? Yv2 : Yv)
template<int MODE>
__global__ __launch_bounds__(256) void gemm_bf16(
    const unsigned short* __restrict__ X, const unsigned short* __restrict__ Wt,
    const float* __restrict__ bias, const float* __restrict__ resid,
    void* __restrict__ Yv, void* __restrict__ Yv2, void* __restrict__ Yv3,
    int N, int K, int kbeg, int kend) {
  __shared__ __align__(16) unsigned short As[128 * 32];
  __shared__ __align__(16) unsigned short Bs[128 * 32];
  const int tid = threadIdx.x;
  const int wid = tid >> 6, lane = tid & 63;
  const int bm = blockIdx.x * 128, bn = blockIdx.y * 128;
  const int wr = wid >> 1, wc = wid & 1;

  const int klen = kend - kbeg;
  const int kb = kbeg + blockIdx.z * klen;
  const int ke = kb + klen;

  f32x4 acc[4][4];
#pragma unroll
  for (int m = 0; m < 4; ++m)
#pragma unroll
    for (int n = 0; n < 4; ++n) acc[m][n] = (f32x4){0.f, 0.f, 0.f, 0.f};

  const int r0 = wid * 2, r1 = wid * 2 + 1;
  const int sr0 = r0 * 16 + (lane >> 2), sr1 = r1 * 16 + (lane >> 2);
  const int seg = (lane & 3) * 8;
  const int fr = lane & 15, kg = lane >> 4;

  for (int k0 = kb; k0 < ke; k0 += 32) {
    __syncthreads();
    gload_lds16(X + (size_t)(bm + sr0) * K + k0 + seg, As + r0 * 512);
    gload_lds16(X + (size_t)(bm + sr1) * K + k0 + seg, As + r1 * 512);
    gload_lds16(Wt + (size_t)(bn + sr0) * K + k0 + seg, Bs + r0 * 512);
    gload_lds16(Wt + (size_t)(bn + sr1) * K + k0 + seg, Bs + r1 * 512);
    __syncthreads();
    bf16x8 a[4], b[4];
#pragma unroll
    for (int m = 0; m < 4; ++m)
      a[m] = *(const bf16x8*)&As[(wr * 64 + m * 16 + fr) * 32 + kg * 8];
#pragma unroll
    for (int n = 0; n < 4; ++n)
      b[n] = *(const bf16x8*)&Bs[(wc * 64 + n * 16 + fr) * 32 + kg * 8];
    __builtin_amdgcn_s_setprio(1);
#pragma unroll
    for (int m = 0; m < 4; ++m)
#pragma unroll
      for (int n = 0; n < 4; ++n)
        acc[m][n] = __builtin_amdgcn_mfma_f32_16x16x32_bf16(a[m], b[n], acc[m][n], 0, 0, 0);
    __builtin_amdgcn_s_setprio(0);
  }

  const int fq = lane >> 4;
#pragma unroll
  for (int m = 0; m < 4; ++m) {
    const int gr0 = bm + wr * 64 + m * 16 + fq * 4;
#pragma unroll
    for (int n = 0; n < 4; ++n) {
      const int gc = bn + wc * 64 + n * 16 + fr;
      if constexpr (MODE == 5) {
        const int sg = gc >> 10, col = gc & 1023;
        const float bv = bias[gc];
        if (sg == 2) {
          ushort4 st;
          st.x = f2b(acc[m][n][0] + bv); st.y = f2b(acc[m][n][1] + bv);
          st.z = f2b(acc[m][n][2] + bv); st.w = f2b(acc[m][n][3] + bv);
          const int bb = gr0 >> 10, s = gr0 & (S_ - 1);
          *(ushort4*)((unsigned short*)Yv3 + ((size_t)(bb * 1024 + col)) * 1024 + s) = st;
        } else {
          unsigned short* tgt = sg ? (unsigned short*)Yv2 : (unsigned short*)Yv;
#pragma unroll
          for (int r = 0; r < 4; ++r)
            tgt[(size_t)(gr0 + r) * 1024 + col] = f2b(acc[m][n][r] + bv);
        }
      } else if constexpr (MODE == 6) {
        float* pz = blockIdx.z ? (float*)Yv2 : (float*)Yv;
#pragma unroll
        for (int r = 0; r < 4; ++r)
          pz[(size_t)(gr0 + r) * N + gc] = acc[m][n][r];
      } else {
        const float bv = bias[gc];
#pragma unroll
        for (int r = 0; r < 4; ++r) {
          const int row = gr0 + r;
          float v = acc[m][n][r] + bv;
          if constexpr (MODE == 1) {
            ((float*)Yv)[(size_t)row * N + gc] = v + resid[(size_t)row * N + gc];
          } else if constexpr (MODE == 2) {
            v = 0.5f * v * (1.f + erff(v * 0.70710678118654752f));
            ((unsigned short*)Yv)[(size_t)row * N + gc] = f2b(v);
          } else {  // MODE 3
            v += resid[(size_t)row * N + gc];
            const int bb = row >> 10, s = row & (S_ - 1);
            ((float*)Yv)[((size_t)(s * B_ + bb)) * D_ + gc] = v;
          }
        }
      }
    }
  }
}

// ---------------- split-K combine + final transposed store ----------------
__global__ __launch_bounds__(256) void combine_kernel(
    const float* __restrict__ p0, const float* __restrict__ p1,
    const float* __restrict__ bias, const float* __restrict__ resid,
    float* __restrict__ out) {
  const int row = blockIdx.x;
  const int col = threadIdx.x * 4;
  const size_t idx = (size_t)row * D_ + col;
  float4 a = *(const float4*)(p0 + idx);
  float4 b = *(const float4*)(p1 + idx);
  float4 r = *(const float4*)(resid + idx);
  float4 bb = *(const float4*)(bias + col);
  float4 v = make_float4(a.x + b.x + r.x + bb.x, a.y + b.y + r.y + bb.y,
                         a.z + b.z + r.z + bb.z, a.w + b.w + r.w + bb.w);
  const int bbi = row >> 10, s = row & (S_ - 1);
  *(float4*)(out + ((size_t)(s * B_ + bbi)) * D_ + col) = v;
}

// ---------------- MFMA relative attention ----------------
// grid: (S/16, B*H), 256 threads = 4 waves. Block: 16 q-rows of one (b,h).
__global__ __launch_bounds__(256) void attn_mfma(
    const unsigned short* __restrict__ Q, const unsigned short* __restrict__ Kb,
    const unsigned short* __restrict__ vT, const unsigned short* __restrict__ relkB,
    const float* __restrict__ relv, unsigned short* __restrict__ Wctx) {
  __shared__ float sc[16 * 1024];      // 64KB f32 scores; P rows rewritten bf16 in place
  __shared__ float qrelp[16 * 113];    // qrel bias, reused as pr bins
  __shared__ float rsum[16];

  const int q0 = blockIdx.x * 16;
  const int bh = blockIdx.y, b = bh >> 4, h = bh & 15;
  const int tid = threadIdx.x, w = tid >> 6, lane = tid & 63;
  const int fr = lane & 15, kg = lane >> 4;
  const size_t base = ((size_t)b * S_) * D_ + h * HD_;

  // Q A-fragments (registers, whole kernel)
  bf16x8 qa0 = *(const bf16x8*)(Q + base + (size_t)(q0 + fr) * D_ + kg * 8);
  bf16x8 qa1 = *(const bf16x8*)(Q + base + (size_t)(q0 + fr) * D_ + 32 + kg * 8);

  // ---- qrel[q][r] = Q-row q . rel_k[r] via MFMA ----
  for (int rt = w; rt < 7; rt += 4) {
    f32x4 c = (f32x4){0.f, 0.f, 0.f, 0.f};
    bf16x8 b0 = *(const bf16x8*)(relkB + (rt * 16 + fr) * 64 + kg * 8);
    bf16x8 b1 = *(const bf16x8*)(relkB + (rt * 16 + fr) * 64 + 32 + kg * 8);
    c = __builtin_amdgcn_mfma_f32_16x16x32_bf16(qa0, b0, c, 0, 0, 0);
    c = __builtin_amdgcn_mfma_f32_16x16x32_bf16(qa1, b1, c, 0, 0, 0);
#pragma unroll
    for (int rr = 0; rr < 4; ++rr)
      qrelp[(kg * 4 + rr) * 113 + rt * 16 + fr] = c[rr];
  }
  __syncthreads();

  // ---- QK^T ----
#pragma unroll 4
  for (int j = 0; j < 16; ++j) {
    const int krow = j * 64 + w * 16 + fr;
    const unsigned short* kp = Kb + base + (size_t)krow * D_ + kg * 8;
    bf16x8 kf0 = *(const bf16x8*)(kp);
    bf16x8 kf1 = *(const bf16x8*)(kp + 32);
    f32x4 c = (f32x4){0.f, 0.f, 0.f, 0.f};
    __builtin_amdgcn_s_setprio(1);
    c = __builtin_amdgcn_mfma_f32_16x16x32_bf16(qa0, kf0, c, 0, 0, 0);
    c = __builtin_amdgcn_mfma_f32_16x16x32_bf16(qa1, kf1, c, 0, 0, 0);
    __builtin_amdgcn_s_setprio(0);
    const int k = krow;
#pragma unroll
    for (int rr = 0; rr < 4; ++rr) {
      const int q = kg * 4 + rr;
      const int ridx = min(max(k - (q0 + q), -50), 50) + 50;
      sc[q * 1024 + swza(k, q)] = (c[rr] + qrelp[q * 113 + ridx]) * 0.125f;
    }
  }
  __syncthreads();

  // ---- softmax + pr bins + in-place normalize/bf16-convert; wave owns rows 4w..4w+3 ----
#pragma unroll
  for (int rq = 0; rq < 4; ++rq) {
    const int q = w * 4 + rq;
    const int s7 = q & 7;
    float* row = sc + q * 1024;
    float m = -1e30f;
#pragma unroll
    for (int it = 0; it < 16; ++it) m = fmaxf(m, row[lane + it * 64]);
    m = wave_red_max(m);
    float sum = 0.f;
#pragma unroll
    for (int it = 0; it < 16; ++it) {
      const float e = __expf(row[lane + it * 64] - m);
      row[lane + it * 64] = e;
      sum += e;
    }
    sum = wave_red_sum(sum);
    if (lane == 0) rsum[q] = sum;
    // pr bins (unnormalized)
    const int qi = q0 + q;
    float* prq = qrelp + q * 113;
    for (int r = lane; r < NREL; r += 64) {
      if (r != 0 && r != 100) {
        const int kk = qi + r - 50;
        prq[r] = (kk >= 0 && kk < S_) ? row[swza(kk, q)] : 0.f;
      }
    }
    float sL = 0.f;
    for (int kk = lane; kk <= qi - 50; kk += 64) sL += row[swza(kk, q)];
    sL = wave_red_sum(sL);
    float sR = 0.f;
    for (int kk = qi + 50 + lane; kk < S_; kk += 64) sR += row[swza(kk, q)];
    sR = wave_red_sum(sR);
    if (lane == 0) { prq[0] = sL; prq[100] = sR; }
    // in-place bf16 conversion: lane handles pairs p = lane + it*64 (k = 2p, 2p+1)
    const float rinv = 1.f / sum;
    float vlo[8], vhi[8];
#pragma unroll
    for (int it = 0; it < 8; ++it) {
      const int p = lane + it * 64;
      const int dw = (((p >> 1) ^ s7) << 2) + (p & 1) * 2;
      const float2 f = *(const float2*)&row[dw];
      vlo[it] = f.x; vhi[it] = f.y;
    }
    unsigned int* rowu = (unsigned int*)row;
#pragma unroll
    for (int it = 0; it < 8; ++it) {
      const int p = lane + it * 64;
      const unsigned int pk = (unsigned int)f2b(vlo[it] * rinv) |
                              ((unsigned int)f2b(vhi[it] * rinv) << 16);
      rowu[(((p >> 2) ^ s7) << 2) + (p & 3)] = pk;
    }
  }
  __syncthreads();

  // ---- PV: A = V^T rows (d), B = P_bf rows (q=fr); pure ds_read+MFMA ----
  const int dtile = w * 16;
  const size_t vtb = ((size_t)(b * 1024 + h * 64 + dtile + fr)) * 1024;
  const unsigned short* pbase = (const unsigned short*)(sc + (size_t)fr * 1024);
  const int f7 = fr & 7;
  f32x4 o = (f32x4){0.f, 0.f, 0.f, 0.f};
  __builtin_amdgcn_s_setprio(1);
#pragma unroll 8
  for (int ks = 0; ks < 32; ++ks) {
    bf16x8 va = *(const bf16x8*)(vT + vtb + ks * 32 + kg * 8);
    bf16x8 pb = *(const bf16x8*)(pbase + (((ks * 4 + kg) ^ f7) << 3));
    o = __builtin_amdgcn_mfma_f32_16x16x32_bf16(va, pb, o, 0, 0, 0);
  }
  __builtin_amdgcn_s_setprio(0);

  // ---- w2 = pr . relv (unnormalized) * rinv, add, packed store ----
  const int q = fr;
  const int dl = kg * 4;
  const float rinv = 1.f / rsum[q];
  f32x4 w2 = (f32x4){0.f, 0.f, 0.f, 0.f};
  const float* prq = qrelp + q * 113;
  for (int r = 0; r < NREL; ++r) {
    const float p = prq[r];
    const float4 rv = *(const float4*)&relv[r * 64 + dtile + dl];
    w2[0] = fmaf(p, rv.x, w2[0]); w2[1] = fmaf(p, rv.y, w2[1]);
    w2[2] = fmaf(p, rv.z, w2[2]); w2[3] = fmaf(p, rv.w, w2[3]);
  }
  ushort4 st;
  st.x = f2b(o[0] + w2[0] * rinv);
  st.y = f2b(o[1] + w2[1] * rinv);
  st.z = f2b(o[2] + w2[2] * rinv);
  st.w = f2b(o[3] + w2[3] * rinv);
  *(ushort4*)(Wctx + base + (size_t)(q0 + q) * D_ + dtile + dl) = st;
}

// ---------------- launch ----------------
extern "C" void kernel_launch(void* const* d_in, const int* in_sizes, int n_in,
                              void* d_out, int out_size, void* d_ws, size_t ws_size,
                              hipStream_t stream) {
  (void)in_sizes; (void)n_in; (void)out_size;
  const float* x      = (const float*)d_in[0];
  const float* Wq     = (const float*)d_in[1];
  const float* bq     = (const float*)d_in[2];
  const float* Wk     = (const float*)d_in[3];
  const float* bk     = (const float*)d_in[4];
  const float* Wv     = (const float*)d_in[5];
  const float* bv     = (const float*)d_in[6];
  const float* Wo     = (const float*)d_in[7];
  const float* bo     = (const float*)d_in[8];
  const float* rel_k  = (const float*)d_in[9];
  const float* rel_v  = (const float*)d_in[10];
  const float* g_attn = (const float*)d_in[11];
  const float* g_ff   = (const float*)d_in[12];
  const float* W_in   = (const float*)d_in[13];
  const float* b_in   = (const float*)d_in[14];
  const float* W_out  = (const float*)d_in[15];
  const float* b_out  = (const float*)d_in[16];
  float* out = (float*)d_out;

  const size_t MB = 1u << 20;
  char* Wp = (char*)d_ws;
  float*          hbF  = (float*)Wp;                          // 16MB; later p0
  unsigned short* hbB  = (unsigned short*)(Wp + 16 * MB);     // 8MB
  unsigned short* qB   = (unsigned short*)(Wp + 24 * MB);     // 8MB
  unsigned short* kB   = (unsigned short*)(Wp + 32 * MB);     // 8MB
  unsigned short* vT   = (unsigned short*)(Wp + 40 * MB);     // 8MB  [b*1024+h*64+d][s]
  unsigned short* wB   = (unsigned short*)(Wp + 48 * MB);     // 8MB
  unsigned short* ff1B = (unsigned short*)(Wp + 24 * MB);     // 32MB overlay (qkv+w dead)
  float*          h2   = (float*)(Wp + 56 * MB);              // 16MB
  unsigned short* fB   = (unsigned short*)(Wp + 72 * MB);     // 8MB
  unsigned short* wqkvB= (unsigned short*)(Wp + 80 * MB);     // 6MB
  unsigned short* woB  = (unsigned short*)(Wp + 86 * MB);     // 2MB
  unsigned short* winB = (unsigned short*)(Wp + 88 * MB);     // 8MB
  unsigned short* woutB= (unsigned short*)(Wp + 96 * MB);     // 8MB
  unsigned short* relkB= (unsigned short*)(Wp + 104 * MB);    // 14KB
  float*          bqkvC= (float*)(Wp + 104 * MB + 16384);     // 12KB
  float*          p0   = hbF;                                 // overlay (dead at FFN down)
  float*          p1   = (float*)(Wp + 105 * MB);             // 16MB (if ws allows)
  const bool splitK = (ws_size >= 121 * MB);

  // 0. all weight converts in one launch + bias concat (d2d async copies)
  hipLaunchKernelGGL(cvt_all, dim3(12295), dim3(256), 0, stream,
                     Wq, Wk, Wv, Wo, W_in, W_out, rel_k,
                     wqkvB, woB, winB, woutB, relkB);
  hipMemcpyAsync(bqkvC,        bq, D_ * sizeof(float), hipMemcpyDeviceToDevice, stream);
  hipMemcpyAsync(bqkvC + D_,   bk, D_ * sizeof(float), hipMemcpyDeviceToDevice, stream);
  hipMemcpyAsync(bqkvC + 2*D_, bv, D_ * sizeof(float), hipMemcpyDeviceToDevice, stream);

  // 1. pre-norm + transpose -> hbB (bf16) + hbF (f32)
  hipLaunchKernelGGL((rmsnorm_kernel<true, true>), dim3(MROWS), dim3(256), 0, stream,
                     x, g_attn, hbB, hbF);
  // 2. fused QKV projection (Q,K row-major; V transposed per-head)
  hipLaunchKernelGGL((gemm_bf16<5>), dim3(MROWS / 128, 3072 / 128), dim3(256), 0, stream,
                     hbB, wqkvB, bqkvC, nullptr, qB, kB, vT, 3072, D_, 0, D_);
  // 3. MFMA relative attention
  hipLaunchKernelGGL(attn_mfma, dim3(S_ / 16, B_ * H_), dim3(256), 0, stream,
                     qB, kB, vT, relkB, rel_v, wB);
  // 4. O-proj + residual -> h2 (f32)
  hipLaunchKernelGGL((gemm_bf16<1>), dim3(MROWS / 128, D_ / 128), dim3(256), 0, stream,
                     wB, woB, bo, hbF, h2, nullptr, nullptr, D_, D_, 0, D_);
  // 5. second rmsnorm -> fB (bf16)
  hipLaunchKernelGGL((rmsnorm_kernel<false, false>), dim3(MROWS), dim3(256), 0, stream,
                     h2, g_ff, fB, nullptr);
  // 6. FFN up + gelu -> ff1B (bf16)
  hipLaunchKernelGGL((gemm_bf16<2>), dim3(MROWS / 128, DFF_ / 128), dim3(256), 0, stream,
                     fB, winB, b_in, nullptr, ff1B, nullptr, nullptr, DFF_, D_, 0, D_);
  // 7. FFN down + residual + transposed store
  if (splitK) {
    hipLaunchKernelGGL((gemm_bf16<6>), dim3(MROWS / 128, D_ / 128, 2), dim3(256), 0, stream,
                       ff1B, woutB, b_out, nullptr, p0, p1, nullptr, D_, DFF_, 0, DFF_ / 2);
    hipLaunchKernelGGL(combine_kernel, dim3(MROWS), dim3(256), 0, stream,
                       p0, p1, b_out, h2, out);
  } else {
    hipLaunchKernelGGL((gemm_bf16<3>), dim3(MROWS / 128, D_ / 128), dim3(256), 0, stream,
                       ff1B, woutB, b_out, h2, out, nullptr, nullptr, D_, DFF_, 0, DFF_);
  }
}

// Round 7
// 539.762 us; speedup vs baseline: 8.6963x; 1.0986x over previous
//
#include <hip/hip_runtime.h>
#include <hip/hip_bf16.h>

#define S_   1024
#define B_   4
#define D_   1024
#define H_   16
#define HD_  64
#define DFF_ 4096
#define NREL 101
#define MROWS (S_*B_)

typedef __attribute__((ext_vector_type(8))) short bf16x8;
typedef __attribute__((ext_vector_type(4))) float f32x4;

__device__ __forceinline__ float b2f(unsigned short u) {
  unsigned int v = ((unsigned int)u) << 16;
  return __builtin_bit_cast(float, v);
}
__device__ __forceinline__ unsigned short f2b(float f) {
  unsigned int v = __builtin_bit_cast(unsigned int, f);
  v += 0x7fffu + ((v >> 16) & 1u);
  return (unsigned short)(v >> 16);
}

__device__ __forceinline__ float wave_red_sum(float v) {
#pragma unroll
  for (int o = 32; o; o >>= 1) v += __shfl_xor(v, o, 64);
  return v;
}

__device__ __forceinline__ void gload_lds16(const void* g, void* l) {
  __builtin_amdgcn_global_load_lds(
      (const __attribute__((address_space(1))) void*)g,
      (__attribute__((address_space(3))) void*)l, 16, 0, 0);
}

// ---------------- one-shot weight conversion (all weights, 1 launch) ----------------
__device__ __forceinline__ void cvt4(const float* s, unsigned short* d, int idx) {
  float4 v = *(const float4*)(s + idx);
  ushort4 o; o.x = f2b(v.x); o.y = f2b(v.y); o.z = f2b(v.z); o.w = f2b(v.w);
  *(ushort4*)(d + idx) = o;
}
__global__ __launch_bounds__(256) void cvt_all(
    const float* __restrict__ Wq, const float* __restrict__ Wk, const float* __restrict__ Wv,
    const float* __restrict__ Wo, const float* __restrict__ W_in, const float* __restrict__ W_out,
    const float* __restrict__ relk,
    unsigned short* __restrict__ wqkvB, unsigned short* __restrict__ woB,
    unsigned short* __restrict__ winB, unsigned short* __restrict__ woutB,
    unsigned short* __restrict__ relkB) {
  int i = (blockIdx.x * 256 + threadIdx.x) * 4;
  const int M1 = 1048576;
  if (i < M1) { cvt4(Wq, wqkvB, i); return; }
  i -= M1;
  if (i < M1) { cvt4(Wk, wqkvB + M1, i); return; }
  i -= M1;
  if (i < M1) { cvt4(Wv, wqkvB + 2 * M1, i); return; }
  i -= M1;
  if (i < M1) { cvt4(Wo, woB, i); return; }
  i -= M1;
  if (i < 4 * M1) { cvt4(W_in, winB, i); return; }
  i -= 4 * M1;
  if (i < 4 * M1) { cvt4(W_out, woutB, i); return; }
  i -= 4 * M1;
  if (i < 7168) {
    if (i < 6464) cvt4(relk, relkB, i);
    else { ushort4 z = {0, 0, 0, 0}; *(ushort4*)(relkB + i) = z; }
  }
}

// ---------------- RMSNorm: f32 in -> bf16 out (+ optional f32 out) ----------------
template<bool TO_BSD, bool WF32>
__global__ __launch_bounds__(256) void rmsnorm_kernel(
    const float* __restrict__ x, const float* __restrict__ g,
    unsigned short* __restrict__ yb, float* __restrict__ yf) {
  const int row = blockIdx.x;
  int orow = row;
  if (TO_BSD) { int s = row >> 2, b = row & 3; orow = b * S_ + s; }  // row = s*B+b
  const float4 v = *(const float4*)(x + (size_t)row * D_ + threadIdx.x * 4);
  float ss = v.x * v.x + v.y * v.y + v.z * v.z + v.w * v.w;
  ss = wave_red_sum(ss);
  __shared__ float red[4];
  if ((threadIdx.x & 63) == 0) red[threadIdx.x >> 6] = ss;
  __syncthreads();
  const float tot = red[0] + red[1] + red[2] + red[3];
  const float inv = 1.f / (sqrtf(tot) * (1.f / 32.f) + 1e-8f);
  const float4 gg = *(const float4*)(g + threadIdx.x * 4);
  const float o0 = gg.x * v.x * inv, o1 = gg.y * v.y * inv;
  const float o2 = gg.z * v.z * inv, o3 = gg.w * v.w * inv;
  const size_t ob = (size_t)orow * D_ + threadIdx.x * 4;
  ushort4 ub; ub.x = f2b(o0); ub.y = f2b(o1); ub.z = f2b(o2); ub.w = f2b(o3);
  *(ushort4*)(yb + ob) = ub;
  if (WF32) { float4 of = make_float4(o0, o1, o2, o3); *(float4*)(yf + ob) = of; }
}

// ---------------- bf16 MFMA GEMM (m97 structure): Y[M,N] = X[M,K] * W[N,K]^T + bias ----------------
// MODE 1: f32  out = acc + bias + resid               (O-proj -> h2)
// MODE 2: bf16 out = gelu(acc + bias)                 (FFN up)
// MODE 3: f32  out[(s*B+b)*D+col] = acc+bias+resid    (final, transposed store)
// MODE 5: fused QKV: seg=gc>>10 -> Q(Yv)/K(Yv2)/V^T(Yv3); bias = concat [3072]
// MODE 6: split-K partial: f32 raw acc -> (z ? Yv2 : Yv)
template<int MODE>
__global__ __launch_bounds__(256) void gemm_bf16(
    const unsigned short* __restrict__ X, const unsigned short* __restrict__ Wt,
    const float* __restrict__ bias, const float* __restrict__ resid,
    void* __restrict__ Yv, void* __restrict__ Yv2, void* __restrict__ Yv3,
    int N, int K, int kbeg, int kend) {
  __shared__ __align__(16) unsigned short As[128 * 32];
  __shared__ __align__(16) unsigned short Bs[128 * 32];
  const int tid = threadIdx.x;
  const int wid = tid >> 6, lane = tid & 63;
  const int bm = blockIdx.x * 128, bn = blockIdx.y * 128;
  const int wr = wid >> 1, wc = wid & 1;

  const int klen = kend - kbeg;
  const int kb = kbeg + blockIdx.z * klen;
  const int ke = kb + klen;

  f32x4 acc[4][4];
#pragma unroll
  for (int m = 0; m < 4; ++m)
#pragma unroll
    for (int n = 0; n < 4; ++n) acc[m][n] = (f32x4){0.f, 0.f, 0.f, 0.f};

  const int r0 = wid * 2, r1 = wid * 2 + 1;
  const int sr0 = r0 * 16 + (lane >> 2), sr1 = r1 * 16 + (lane >> 2);
  const int seg = (lane & 3) * 8;
  const int fr = lane & 15, kg = lane >> 4;

  for (int k0 = kb; k0 < ke; k0 += 32) {
    __syncthreads();
    gload_lds16(X + (size_t)(bm + sr0) * K + k0 + seg, As + r0 * 512);
    gload_lds16(X + (size_t)(bm + sr1) * K + k0 + seg, As + r1 * 512);
    gload_lds16(Wt + (size_t)(bn + sr0) * K + k0 + seg, Bs + r0 * 512);
    gload_lds16(Wt + (size_t)(bn + sr1) * K + k0 + seg, Bs + r1 * 512);
    __syncthreads();
    bf16x8 a[4], b[4];
#pragma unroll
    for (int m = 0; m < 4; ++m)
      a[m] = *(const bf16x8*)&As[(wr * 64 + m * 16 + fr) * 32 + kg * 8];
#pragma unroll
    for (int n = 0; n < 4; ++n)
      b[n] = *(const bf16x8*)&Bs[(wc * 64 + n * 16 + fr) * 32 + kg * 8];
    __builtin_amdgcn_s_setprio(1);
#pragma unroll
    for (int m = 0; m < 4; ++m)
#pragma unroll
      for (int n = 0; n < 4; ++n)
        acc[m][n] = __builtin_amdgcn_mfma_f32_16x16x32_bf16(a[m], b[n], acc[m][n], 0, 0, 0);
    __builtin_amdgcn_s_setprio(0);
  }

  const int fq = lane >> 4;
#pragma unroll
  for (int m = 0; m < 4; ++m) {
    const int gr0 = bm + wr * 64 + m * 16 + fq * 4;
#pragma unroll
    for (int n = 0; n < 4; ++n) {
      const int gc = bn + wc * 64 + n * 16 + fr;
      if constexpr (MODE == 5) {
        const int sg = gc >> 10, col = gc & 1023;
        const float bv = bias[gc];
        if (sg == 2) {
          ushort4 st;
          st.x = f2b(acc[m][n][0] + bv); st.y = f2b(acc[m][n][1] + bv);
          st.z = f2b(acc[m][n][2] + bv); st.w = f2b(acc[m][n][3] + bv);
          const int bb = gr0 >> 10, s = gr0 & (S_ - 1);
          *(ushort4*)((unsigned short*)Yv3 + ((size_t)(bb * 1024 + col)) * 1024 + s) = st;
        } else {
          unsigned short* tgt = sg ? (unsigned short*)Yv2 : (unsigned short*)Yv;
#pragma unroll
          for (int r = 0; r < 4; ++r)
            tgt[(size_t)(gr0 + r) * 1024 + col] = f2b(acc[m][n][r] + bv);
        }
      } else if constexpr (MODE == 6) {
        float* pz = blockIdx.z ? (float*)Yv2 : (float*)Yv;
#pragma unroll
        for (int r = 0; r < 4; ++r)
          pz[(size_t)(gr0 + r) * N + gc] = acc[m][n][r];
      } else {
        const float bv = bias[gc];
#pragma unroll
        for (int r = 0; r < 4; ++r) {
          const int row = gr0 + r;
          float v = acc[m][n][r] + bv;
          if constexpr (MODE == 1) {
            ((float*)Yv)[(size_t)row * N + gc] = v + resid[(size_t)row * N + gc];
          } else if constexpr (MODE == 2) {
            v = 0.5f * v * (1.f + erff(v * 0.70710678118654752f));
            ((unsigned short*)Yv)[(size_t)row * N + gc] = f2b(v);
          } else {  // MODE 3
            v += resid[(size_t)row * N + gc];
            const int bb = row >> 10, s = row & (S_ - 1);
            ((float*)Yv)[((size_t)(s * B_ + bb)) * D_ + gc] = v;
          }
        }
      }
    }
  }
}

// ---------------- split-K combine + final transposed store ----------------
__global__ __launch_bounds__(256) void combine_kernel(
    const float* __restrict__ p0, const float* __restrict__ p1,
    const float* __restrict__ bias, const float* __restrict__ resid,
    float* __restrict__ out) {
  const int row = blockIdx.x;
  const int col = threadIdx.x * 4;
  const size_t idx = (size_t)row * D_ + col;
  float4 a = *(const float4*)(p0 + idx);
  float4 b = *(const float4*)(p1 + idx);
  float4 r = *(const float4*)(resid + idx);
  float4 bb = *(const float4*)(bias + col);
  float4 v = make_float4(a.x + b.x + r.x + bb.x, a.y + b.y + r.y + bb.y,
                         a.z + b.z + r.z + bb.z, a.w + b.w + r.w + bb.w);
  const int bbi = row >> 10, s = row & (S_ - 1);
  *(float4*)(out + ((size_t)(s * B_ + bbi)) * D_ + col) = v;
}

// ---------------- MFMA relative attention, register-resident scores ----------------
// grid: (S/16, B*H), 256 threads = 4 waves. Block: 16 q-rows of one (b,h).
// Wave w owns k-columns {j*64 + w*16 + fr} for j=0..15 (its 256 of 1024 k).
__global__ __launch_bounds__(256, 4) void attn_mfma(
    const unsigned short* __restrict__ Q, const unsigned short* __restrict__ Kb,
    const unsigned short* __restrict__ vT, const unsigned short* __restrict__ relkB,
    const float* __restrict__ relv, unsigned short* __restrict__ Wctx) {
  __shared__ unsigned short Pb[16 * 1024];   // 32KB bf16 P (unnormalized exp), swizzled
  __shared__ float qrelp[16 * 112];          // 7KB qrel bias
  __shared__ float redmx[16 * 4];            // cross-wave max partials
  __shared__ float redsm[16 * 4];            // cross-wave sum partials
  __shared__ float prp[2 * 16 * 4];          // sL / sR partials
  // total: 40960 B exactly -> 4 blocks/CU

  const int q0 = blockIdx.x * 16;
  const int bh = blockIdx.y, b = bh >> 4, h = bh & 15;
  const int tid = threadIdx.x, w = tid >> 6, lane = tid & 63;
  const int fr = lane & 15, kg = lane >> 4;
  const size_t base = ((size_t)b * S_) * D_ + h * HD_;

  // Q A-fragments (registers, whole kernel)
  bf16x8 qa0 = *(const bf16x8*)(Q + base + (size_t)(q0 + fr) * D_ + kg * 8);
  bf16x8 qa1 = *(const bf16x8*)(Q + base + (size_t)(q0 + fr) * D_ + 32 + kg * 8);

  // ---- qrel[q][r] = Q-row q . rel_k[r] via MFMA (stride 112) ----
  for (int rt = w; rt < 7; rt += 4) {
    f32x4 c = (f32x4){0.f, 0.f, 0.f, 0.f};
    bf16x8 b0 = *(const bf16x8*)(relkB + (rt * 16 + fr) * 64 + kg * 8);
    bf16x8 b1 = *(const bf16x8*)(relkB + (rt * 16 + fr) * 64 + 32 + kg * 8);
    c = __builtin_amdgcn_mfma_f32_16x16x32_bf16(qa0, b0, c, 0, 0, 0);
    c = __builtin_amdgcn_mfma_f32_16x16x32_bf16(qa1, b1, c, 0, 0, 0);
#pragma unroll
    for (int rr = 0; rr < 4; ++rr)
      qrelp[(kg * 4 + rr) * 112 + rt * 16 + fr] = c[rr];
  }
  __syncthreads();

  // ---- QK^T into registers: c[j][rr] = score(q=kg*4+rr, k=j*64+w*16+fr) ----
  const int kbase = w * 16 + fr;
  f32x4 c[16];
#pragma unroll
  for (int j = 0; j < 16; ++j) {
    const unsigned short* kp = Kb + base + (size_t)(j * 64 + kbase) * D_ + kg * 8;
    bf16x8 kf0 = *(const bf16x8*)(kp);
    bf16x8 kf1 = *(const bf16x8*)(kp + 32);
    f32x4 t = (f32x4){0.f, 0.f, 0.f, 0.f};
    t = __builtin_amdgcn_mfma_f32_16x16x32_bf16(qa0, kf0, t, 0, 0, 0);
    t = __builtin_amdgcn_mfma_f32_16x16x32_bf16(qa1, kf1, t, 0, 0, 0);
    c[j] = t;
  }
  // bias + scale (in-register)
#pragma unroll
  for (int j = 0; j < 16; ++j) {
    const int k = j * 64 + kbase;
#pragma unroll
    for (int rr = 0; rr < 4; ++rr) {
      const int q = kg * 4 + rr;
      const int ridx = min(max(k - (q0 + q), -50), 50) + 50;
      c[j][rr] = (c[j][rr] + qrelp[q * 112 + ridx]) * 0.125f;
    }
  }

  // ---- in-register row max over this wave's 256 k, then cross-wave ----
  float mx[4];
#pragma unroll
  for (int rr = 0; rr < 4; ++rr) {
    float m = c[0][rr];
#pragma unroll
    for (int j = 1; j < 16; ++j) m = fmaxf(m, c[j][rr]);
#pragma unroll
    for (int o = 1; o <= 8; o <<= 1) m = fmaxf(m, __shfl_xor(m, o, 64));
    mx[rr] = m;
  }
  if (fr == 0) {
#pragma unroll
    for (int rr = 0; rr < 4; ++rr) redmx[(kg * 4 + rr) * 4 + w] = mx[rr];
  }
  __syncthreads();
  float m[4];
#pragma unroll
  for (int rr = 0; rr < 4; ++rr) {
    const int q = kg * 4 + rr;
    m[rr] = fmaxf(fmaxf(redmx[q * 4 + 0], redmx[q * 4 + 1]),
                  fmaxf(redmx[q * 4 + 2], redmx[q * 4 + 3]));
  }

  // ---- exp (in-register, unnormalized) ----
#pragma unroll
  for (int j = 0; j < 16; ++j)
#pragma unroll
    for (int rr = 0; rr < 4; ++rr) c[j][rr] = __expf(c[j][rr] - m[rr]);

  // ---- row sums + boundary bin sums (sL: dist<=-50, sR: dist>=50) ----
  float sm[4], sl[4], sr4[4];
#pragma unroll
  for (int rr = 0; rr < 4; ++rr) { sm[rr] = 0.f; sl[rr] = 0.f; sr4[rr] = 0.f; }
#pragma unroll
  for (int j = 0; j < 16; ++j) {
    const int k = j * 64 + kbase;
#pragma unroll
    for (int rr = 0; rr < 4; ++rr) {
      const int d = k - (q0 + kg * 4 + rr);
      const float e = c[j][rr];
      sm[rr] += e;
      sl[rr] += (d <= -50) ? e : 0.f;
      sr4[rr] += (d >= 50) ? e : 0.f;
    }
  }
#pragma unroll
  for (int rr = 0; rr < 4; ++rr) {
#pragma unroll
    for (int o = 1; o <= 8; o <<= 1) {
      sm[rr] += __shfl_xor(sm[rr], o, 64);
      sl[rr] += __shfl_xor(sl[rr], o, 64);
      sr4[rr] += __shfl_xor(sr4[rr], o, 64);
    }
  }
  if (fr == 0) {
#pragma unroll
    for (int rr = 0; rr < 4; ++rr) {
      const int q = kg * 4 + rr;
      redsm[q * 4 + w] = sm[rr];
      prp[q * 4 + w] = sl[rr];
      prp[64 + q * 4 + w] = sr4[rr];
    }
  }

  // ---- P write: bf16, swizzled granules (granule ^ (q&7) ^ ((q&8)>>2)) ----
#pragma unroll
  for (int j = 0; j < 16; ++j) {
    const int k = j * 64 + kbase;
    const int g = k >> 3, kl = k & 7;
#pragma unroll
    for (int rr = 0; rr < 4; ++rr) {
      const int q = kg * 4 + rr;
      const int swb = (q & 7) ^ ((q & 8) >> 2);
      Pb[q * 1024 + ((g ^ swb) << 3) + kl] = f2b(c[j][rr]);
    }
  }
  __syncthreads();

  // ---- PV (O^T): A = vT rows (d), B = P rows (q=fr); unnormalized ----
  const int dtile = w * 16;
  const size_t vtb = ((size_t)(b * 1024 + h * 64 + dtile + fr)) * 1024;
  const int swbf = (fr & 7) ^ ((fr & 8) >> 2);
  const unsigned short* pbase = Pb + fr * 1024;
  f32x4 o = (f32x4){0.f, 0.f, 0.f, 0.f};
  __builtin_amdgcn_s_setprio(1);
#pragma unroll 8
  for (int ks = 0; ks < 32; ++ks) {
    bf16x8 va = *(const bf16x8*)(vT + vtb + ks * 32 + kg * 8);
    bf16x8 pb = *(const bf16x8*)(pbase + (((ks * 4 + kg) ^ swbf) << 3));
    o = __builtin_amdgcn_mfma_f32_16x16x32_bf16(va, pb, o, 0, 0, 0);
  }
  __builtin_amdgcn_s_setprio(0);

  // ---- epilogue: w2 from bf16 P bins + boundary sums; normalize; store ----
  const int q = fr;                    // col of O^T held by this lane
  const int dl = kg * 4;               // d rows dl..dl+3 within wave's d-tile
  const float rs = redsm[q * 4 + 0] + redsm[q * 4 + 1] +
                   redsm[q * 4 + 2] + redsm[q * 4 + 3];
  const float rinv = 1.f / rs;
  const float slt = prp[q * 4 + 0] + prp[q * 4 + 1] + prp[q * 4 + 2] + prp[q * 4 + 3];
  const float srt = prp[64 + q * 4 + 0] + prp[64 + q * 4 + 1] +
                    prp[64 + q * 4 + 2] + prp[64 + q * 4 + 3];
  f32x4 w2;
  {
    const float4 rv0 = *(const float4*)&relv[0 * 64 + dtile + dl];
    const float4 rv100 = *(const float4*)&relv[100 * 64 + dtile + dl];
    w2[0] = slt * rv0.x + srt * rv100.x;
    w2[1] = slt * rv0.y + srt * rv100.y;
    w2[2] = slt * rv0.z + srt * rv100.z;
    w2[3] = slt * rv0.w + srt * rv100.w;
  }
  const int qi = q0 + q;
  const unsigned short* prow = Pb + q * 1024;
#pragma unroll 4
  for (int r = 1; r < 100; ++r) {
    const int k = qi + r - 50;
    float p = 0.f;
    if (k >= 0 && k < S_)
      p = b2f(prow[(((k >> 3) ^ swbf) << 3) + (k & 7)]);
    const float4 rv = *(const float4*)&relv[r * 64 + dtile + dl];
    w2[0] = fmaf(p, rv.x, w2[0]); w2[1] = fmaf(p, rv.y, w2[1]);
    w2[2] = fmaf(p, rv.z, w2[2]); w2[3] = fmaf(p, rv.w, w2[3]);
  }
  ushort4 st;
  st.x = f2b((o[0] + w2[0]) * rinv);
  st.y = f2b((o[1] + w2[1]) * rinv);
  st.z = f2b((o[2] + w2[2]) * rinv);
  st.w = f2b((o[3] + w2[3]) * rinv);
  *(ushort4*)(Wctx + base + (size_t)qi * D_ + dtile + dl) = st;
}

// ---------------- launch ----------------
extern "C" void kernel_launch(void* const* d_in, const int* in_sizes, int n_in,
                              void* d_out, int out_size, void* d_ws, size_t ws_size,
                              hipStream_t stream) {
  (void)in_sizes; (void)n_in; (void)out_size;
  const float* x      = (const float*)d_in[0];
  const float* Wq     = (const float*)d_in[1];
  const float* bq     = (const float*)d_in[2];
  const float* Wk     = (const float*)d_in[3];
  const float* bk     = (const float*)d_in[4];
  const float* Wv     = (const float*)d_in[5];
  const float* bv     = (const float*)d_in[6];
  const float* Wo     = (const float*)d_in[7];
  const float* bo     = (const float*)d_in[8];
  const float* rel_k  = (const float*)d_in[9];
  const float* rel_v  = (const float*)d_in[10];
  const float* g_attn = (const float*)d_in[11];
  const float* g_ff   = (const float*)d_in[12];
  const float* W_in   = (const float*)d_in[13];
  const float* b_in   = (const float*)d_in[14];
  const float* W_out  = (const float*)d_in[15];
  const float* b_out  = (const float*)d_in[16];
  float* out = (float*)d_out;

  const size_t MB = 1u << 20;
  char* Wp = (char*)d_ws;
  float*          hbF  = (float*)Wp;                          // 16MB; later p0
  unsigned short* hbB  = (unsigned short*)(Wp + 16 * MB);     // 8MB
  unsigned short* qB   = (unsigned short*)(Wp + 24 * MB);     // 8MB
  unsigned short* kB   = (unsigned short*)(Wp + 32 * MB);     // 8MB
  unsigned short* vT   = (unsigned short*)(Wp + 40 * MB);     // 8MB  [b*1024+h*64+d][s]
  unsigned short* wB   = (unsigned short*)(Wp + 48 * MB);     // 8MB
  unsigned short* ff1B = (unsigned short*)(Wp + 24 * MB);     // 32MB overlay (qkv+w dead)
  float*          h2   = (float*)(Wp + 56 * MB);              // 16MB
  unsigned short* fB   = (unsigned short*)(Wp + 72 * MB);     // 8MB
  unsigned short* wqkvB= (unsigned short*)(Wp + 80 * MB);     // 6MB
  unsigned short* woB  = (unsigned short*)(Wp + 86 * MB);     // 2MB
  unsigned short* winB = (unsigned short*)(Wp + 88 * MB);     // 8MB
  unsigned short* woutB= (unsigned short*)(Wp + 96 * MB);     // 8MB
  unsigned short* relkB= (unsigned short*)(Wp + 104 * MB);    // 14KB
  float*          bqkvC= (float*)(Wp + 104 * MB + 16384);     // 12KB
  float*          p0   = hbF;                                 // overlay (dead at FFN down)
  float*          p1   = (float*)(Wp + 105 * MB);             // 16MB (if ws allows)
  const bool splitK = (ws_size >= 121 * MB);

  // 0. all weight converts in one launch + bias concat (d2d async copies)
  hipLaunchKernelGGL(cvt_all, dim3(12295), dim3(256), 0, stream,
                     Wq, Wk, Wv, Wo, W_in, W_out, rel_k,
                     wqkvB, woB, winB, woutB, relkB);
  hipMemcpyAsync(bqkvC,        bq, D_ * sizeof(float), hipMemcpyDeviceToDevice, stream);
  hipMemcpyAsync(bqkvC + D_,   bk, D_ * sizeof(float), hipMemcpyDeviceToDevice, stream);
  hipMemcpyAsync(bqkvC + 2*D_, bv, D_ * sizeof(float), hipMemcpyDeviceToDevice, stream);

  // 1. pre-norm + transpose -> hbB (bf16) + hbF (f32)
  hipLaunchKernelGGL((rmsnorm_kernel<true, true>), dim3(MROWS), dim3(256), 0, stream,
                     x, g_attn, hbB, hbF);
  // 2. fused QKV projection (Q,K row-major; V transposed per-head)
  hipLaunchKernelGGL((gemm_bf16<5>), dim3(MROWS / 128, 3072 / 128), dim3(256), 0, stream,
                     hbB, wqkvB, bqkvC, nullptr, qB, kB, vT, 3072, D_, 0, D_);
  // 3. MFMA relative attention (register-resident scores)
  hipLaunchKernelGGL(attn_mfma, dim3(S_ / 16, B_ * H_), dim3(256), 0, stream,
                     qB, kB, vT, relkB, rel_v, wB);
  // 4. O-proj + residual -> h2 (f32)
  hipLaunchKernelGGL((gemm_bf16<1>), dim3(MROWS / 128, D_ / 128), dim3(256), 0, stream,
                     wB, woB, bo, hbF, h2, nullptr, nullptr, D_, D_, 0, D_);
  // 5. second rmsnorm -> fB (bf16)
  hipLaunchKernelGGL((rmsnorm_kernel<false, false>), dim3(MROWS), dim3(256), 0, stream,
                     h2, g_ff, fB, nullptr);
  // 6. FFN up + gelu -> ff1B (bf16)
  hipLaunchKernelGGL((gemm_bf16<2>), dim3(MROWS / 128, DFF_ / 128), dim3(256), 0, stream,
                     fB, winB, b_in, nullptr, ff1B, nullptr, nullptr, DFF_, D_, 0, D_);
  // 7. FFN down + residual + transposed store
  if (splitK) {
    hipLaunchKernelGGL((gemm_bf16<6>), dim3(MROWS / 128, D_ / 128, 2), dim3(256), 0, stream,
                       ff1B, woutB, b_out, nullptr, p0, p1, nullptr, D_, DFF_, 0, DFF_ / 2);
    hipLaunchKernelGGL(combine_kernel, dim3(MROWS), dim3(256), 0, stream,
                       p0, p1, b_out, h2, out);
  } else {
    hipLaunchKernelGGL((gemm_bf16<3>), dim3(MROWS / 128, D_ / 128), dim3(256), 0, stream,
                       ff1B, woutB, b_out, h2, out, nullptr, nullptr, D_, DFF_, 0, DFF_);
  }
}

// Round 8
// 481.931 us; speedup vs baseline: 9.7399x; 1.1200x over previous
//
#include <hip/hip_runtime.h>
#include <hip/hip_bf16.h>

#define S_   1024
#define B_   4
#define D_   1024
#define H_   16
#define HD_  64
#define DFF_ 4096
#define NREL 101
#define MROWS (S_*B_)

typedef __attribute__((ext_vector_type(8))) short bf16x8;
typedef __attribute__((ext_vector_type(4))) float f32x4;

__device__ __forceinline__ float b2f(unsigned short u) {
  unsigned int v = ((unsigned int)u) << 16;
  return __builtin_bit_cast(float, v);
}
__device__ __forceinline__ unsigned short f2b(float f) {
  unsigned int v = __builtin_bit_cast(unsigned int, f);
  v += 0x7fffu + ((v >> 16) & 1u);
  return (unsigned short)(v >> 16);
}

__device__ __forceinline__ float wave_red_sum(float v) {
#pragma unroll
  for (int o = 32; o; o >>= 1) v += __shfl_xor(v, o, 64);
  return v;
}

__device__ __forceinline__ void gload_lds16(const void* g, void* l) {
  __builtin_amdgcn_global_load_lds(
      (const __attribute__((address_space(1))) void*)g,
      (__attribute__((address_space(3))) void*)l, 16, 0, 0);
}

// ---------------- one-shot weight conversion (all weights, 1 launch) ----------------
__device__ __forceinline__ void cvt4(const float* s, unsigned short* d, int idx) {
  float4 v = *(const float4*)(s + idx);
  ushort4 o; o.x = f2b(v.x); o.y = f2b(v.y); o.z = f2b(v.z); o.w = f2b(v.w);
  *(ushort4*)(d + idx) = o;
}
__global__ __launch_bounds__(256) void cvt_all(
    const float* __restrict__ Wq, const float* __restrict__ Wk, const float* __restrict__ Wv,
    const float* __restrict__ Wo, const float* __restrict__ W_in, const float* __restrict__ W_out,
    const float* __restrict__ relk, const float* __restrict__ relv,
    unsigned short* __restrict__ wqkvB, unsigned short* __restrict__ woB,
    unsigned short* __restrict__ winB, unsigned short* __restrict__ woutB,
    unsigned short* __restrict__ relkB, unsigned short* __restrict__ relvT) {
  int i = (blockIdx.x * 256 + threadIdx.x) * 4;
  const int M1 = 1048576;
  if (i < M1) { cvt4(Wq, wqkvB, i); return; }
  i -= M1;
  if (i < M1) { cvt4(Wk, wqkvB + M1, i); return; }
  i -= M1;
  if (i < M1) { cvt4(Wv, wqkvB + 2 * M1, i); return; }
  i -= M1;
  if (i < M1) { cvt4(Wo, woB, i); return; }
  i -= M1;
  if (i < 4 * M1) { cvt4(W_in, winB, i); return; }
  i -= 4 * M1;
  if (i < 4 * M1) { cvt4(W_out, woutB, i); return; }
  i -= 4 * M1;
  if (i < 7168) {
    if (i < 6464) cvt4(relk, relkB, i);
    else { ushort4 z = {0, 0, 0, 0}; *(ushort4*)(relkB + i) = z; }
    return;
  }
  i -= 7168;
  if (i < 8192) {
    // relvT[d][r] = relv[r][d], zero-padded to r<128 (4 consecutive r, same d)
    const int d = i >> 7, r = i & 127;
    ushort4 o;
    o.x = (r     < NREL) ? f2b(relv[(r    ) * 64 + d]) : (unsigned short)0;
    o.y = (r + 1 < NREL) ? f2b(relv[(r + 1) * 64 + d]) : (unsigned short)0;
    o.z = (r + 2 < NREL) ? f2b(relv[(r + 2) * 64 + d]) : (unsigned short)0;
    o.w = (r + 3 < NREL) ? f2b(relv[(r + 3) * 64 + d]) : (unsigned short)0;
    *(ushort4*)(relvT + i) = o;
  }
}

// ---------------- RMSNorm: f32 in -> bf16 out (+ optional f32 out) ----------------
template<bool TO_BSD, bool WF32>
__global__ __launch_bounds__(256) void rmsnorm_kernel(
    const float* __restrict__ x, const float* __restrict__ g,
    unsigned short* __restrict__ yb, float* __restrict__ yf) {
  const int row = blockIdx.x;
  int orow = row;
  if (TO_BSD) { int s = row >> 2, b = row & 3; orow = b * S_ + s; }  // row = s*B+b
  const float4 v = *(const float4*)(x + (size_t)row * D_ + threadIdx.x * 4);
  float ss = v.x * v.x + v.y * v.y + v.z * v.z + v.w * v.w;
  ss = wave_red_sum(ss);
  __shared__ float red[4];
  if ((threadIdx.x & 63) == 0) red[threadIdx.x >> 6] = ss;
  __syncthreads();
  const float tot = red[0] + red[1] + red[2] + red[3];
  const float inv = 1.f / (sqrtf(tot) * (1.f / 32.f) + 1e-8f);
  const float4 gg = *(const float4*)(g + threadIdx.x * 4);
  const float o0 = gg.x * v.x * inv, o1 = gg.y * v.y * inv;
  const float o2 = gg.z * v.z * inv, o3 = gg.w * v.w * inv;
  const size_t ob = (size_t)orow * D_ + threadIdx.x * 4;
  ushort4 ub; ub.x = f2b(o0); ub.y = f2b(o1); ub.z = f2b(o2); ub.w = f2b(o3);
  *(ushort4*)(yb + ob) = ub;
  if (WF32) { float4 of = make_float4(o0, o1, o2, o3); *(float4*)(yf + ob) = of; }
}

// ---------------- bf16 MFMA GEMM (m97 structure): Y[M,N] = X[M,K] * W[N,K]^T + bias ----------------
// MODE 1: f32  out = acc + bias + resid               (O-proj -> h2)
// MODE 2: bf16 out = gelu(acc + bias)                 (FFN up)
// MODE 3: f32  out[(s*B+b)*D+col] = acc+bias+resid    (final, transposed store)
// MODE 5: fused QKV: seg=gc>>10 -> Q(Yv)/K(Yv2)/V^T(Yv3); bias = concat [3072]
// MODE 6: split-K partial: f32 raw acc -> (z ? Yv2 : Yv)
template<int MODE>
__global__ __launch_bounds__(256) void gemm_bf16(
    const unsigned short* __restrict__ X, const unsigned short* __restrict__ Wt,
    const float* __restrict__ bias, const float* __restrict__ resid,
    void* __restrict__ Yv, void* __restrict__ Yv2, void* __restrict__ Yv3,
    int N, int K, int kbeg, int kend) {
  __shared__ __align__(16) unsigned short As[128 * 32];
  __shared__ __align__(16) unsigned short Bs[128 * 32];
  const int tid = threadIdx.x;
  const int wid = tid >> 6, lane = tid & 63;
  const int bm = blockIdx.x * 128, bn = blockIdx.y * 128;
  const int wr = wid >> 1, wc = wid & 1;

  const int klen = kend - kbeg;
  const int kb = kbeg + blockIdx.z * klen;
  const int ke = kb + klen;

  f32x4 acc[4][4];
#pragma unroll
  for (int m = 0; m < 4; ++m)
#pragma unroll
    for (int n = 0; n < 4; ++n) acc[m][n] = (f32x4){0.f, 0.f, 0.f, 0.f};

  const int r0 = wid * 2, r1 = wid * 2 + 1;
  const int sr0 = r0 * 16 + (lane >> 2), sr1 = r1 * 16 + (lane >> 2);
  const int seg = (lane & 3) * 8;
  const int fr = lane & 15, kg = lane >> 4;

  for (int k0 = kb; k0 < ke; k0 += 32) {
    __syncthreads();
    gload_lds16(X + (size_t)(bm + sr0) * K + k0 + seg, As + r0 * 512);
    gload_lds16(X + (size_t)(bm + sr1) * K + k0 + seg, As + r1 * 512);
    gload_lds16(Wt + (size_t)(bn + sr0) * K + k0 + seg, Bs + r0 * 512);
    gload_lds16(Wt + (size_t)(bn + sr1) * K + k0 + seg, Bs + r1 * 512);
    __syncthreads();
    bf16x8 a[4], b[4];
#pragma unroll
    for (int m = 0; m < 4; ++m)
      a[m] = *(const bf16x8*)&As[(wr * 64 + m * 16 + fr) * 32 + kg * 8];
#pragma unroll
    for (int n = 0; n < 4; ++n)
      b[n] = *(const bf16x8*)&Bs[(wc * 64 + n * 16 + fr) * 32 + kg * 8];
    __builtin_amdgcn_s_setprio(1);
#pragma unroll
    for (int m = 0; m < 4; ++m)
#pragma unroll
      for (int n = 0; n < 4; ++n)
        acc[m][n] = __builtin_amdgcn_mfma_f32_16x16x32_bf16(a[m], b[n], acc[m][n], 0, 0, 0);
    __builtin_amdgcn_s_setprio(0);
  }

  const int fq = lane >> 4;
#pragma unroll
  for (int m = 0; m < 4; ++m) {
    const int gr0 = bm + wr * 64 + m * 16 + fq * 4;
#pragma unroll
    for (int n = 0; n < 4; ++n) {
      const int gc = bn + wc * 64 + n * 16 + fr;
      if constexpr (MODE == 5) {
        const int sg = gc >> 10, col = gc & 1023;
        const float bv = bias[gc];
        if (sg == 2) {
          ushort4 st;
          st.x = f2b(acc[m][n][0] + bv); st.y = f2b(acc[m][n][1] + bv);
          st.z = f2b(acc[m][n][2] + bv); st.w = f2b(acc[m][n][3] + bv);
          const int bb = gr0 >> 10, s = gr0 & (S_ - 1);
          *(ushort4*)((unsigned short*)Yv3 + ((size_t)(bb * 1024 + col)) * 1024 + s) = st;
        } else {
          unsigned short* tgt = sg ? (unsigned short*)Yv2 : (unsigned short*)Yv;
#pragma unroll
          for (int r = 0; r < 4; ++r)
            tgt[(size_t)(gr0 + r) * 1024 + col] = f2b(acc[m][n][r] + bv);
        }
      } else if constexpr (MODE == 6) {
        float* pz = blockIdx.z ? (float*)Yv2 : (float*)Yv;
#pragma unroll
        for (int r = 0; r < 4; ++r)
          pz[(size_t)(gr0 + r) * N + gc] = acc[m][n][r];
      } else {
        const float bv = bias[gc];
#pragma unroll
        for (int r = 0; r < 4; ++r) {
          const int row = gr0 + r;
          float v = acc[m][n][r] + bv;
          if constexpr (MODE == 1) {
            ((float*)Yv)[(size_t)row * N + gc] = v + resid[(size_t)row * N + gc];
          } else if constexpr (MODE == 2) {
            v = 0.5f * v * (1.f + erff(v * 0.70710678118654752f));
            ((unsigned short*)Yv)[(size_t)row * N + gc] = f2b(v);
          } else {  // MODE 3
            v += resid[(size_t)row * N + gc];
            const int bb = row >> 10, s = row & (S_ - 1);
            ((float*)Yv)[((size_t)(s * B_ + bb)) * D_ + gc] = v;
          }
        }
      }
    }
  }
}

// ---------------- split-K combine + final transposed store ----------------
__global__ __launch_bounds__(256) void combine_kernel(
    const float* __restrict__ p0, const float* __restrict__ p1,
    const float* __restrict__ bias, const float* __restrict__ resid,
    float* __restrict__ out) {
  const int row = blockIdx.x;
  const int col = threadIdx.x * 4;
  const size_t idx = (size_t)row * D_ + col;
  float4 a = *(const float4*)(p0 + idx);
  float4 b = *(const float4*)(p1 + idx);
  float4 r = *(const float4*)(resid + idx);
  float4 bb = *(const float4*)(bias + col);
  float4 v = make_float4(a.x + b.x + r.x + bb.x, a.y + b.y + r.y + bb.y,
                         a.z + b.z + r.z + bb.z, a.w + b.w + r.w + bb.w);
  const int bbi = row >> 10, s = row & (S_ - 1);
  *(float4*)(out + ((size_t)(s * B_ + bbi)) * D_ + col) = v;
}

// ---------------- MFMA relative attention, register-resident scores ----------------
// grid: 1D 4096 with XCD-aware decode (same-head blocks share XCD L2).
// 256 threads = 4 waves; block = 16 q-rows of one (b,h).
__global__ __launch_bounds__(256, 4) void attn_mfma(
    const unsigned short* __restrict__ Q, const unsigned short* __restrict__ Kb,
    const unsigned short* __restrict__ vT, const unsigned short* __restrict__ relkB,
    const unsigned short* __restrict__ relvT, unsigned short* __restrict__ Wctx) {
  __shared__ unsigned short Pb[16 * 1024];   // 32KB bf16 P (unnormalized exp), swizzled
  __shared__ float qrelp[16 * 112];          // 7KB qrel bias; later aliased by prb
  __shared__ float redmx[16 * 4];            // cross-wave max partials
  __shared__ float redsm[16 * 4];            // cross-wave sum partials
  __shared__ float prp[2 * 16 * 4];          // sL / sR partials
  // total: 40960 B exactly -> 4 blocks/CU

  // XCD-aware decode: bh = (id&7)*8 + ((id>>3)&7); all 64 q-tiles of a head
  // share id%8 -> same XCD residue -> per-XCD K/V working set = 8 heads = 2MB < 4MB L2.
  const int id = blockIdx.x;
  const int low = id & 63;
  const int bh = (low & 7) * 8 + (low >> 3);
  const int q0 = (id >> 6) * 16;
  const int b = bh >> 4, h = bh & 15;
  const int tid = threadIdx.x, w = tid >> 6, lane = tid & 63;
  const int fr = lane & 15, kg = lane >> 4;
  const size_t base = ((size_t)b * S_) * D_ + h * HD_;

  // Q A-fragments (registers, whole kernel)
  bf16x8 qa0 = *(const bf16x8*)(Q + base + (size_t)(q0 + fr) * D_ + kg * 8);
  bf16x8 qa1 = *(const bf16x8*)(Q + base + (size_t)(q0 + fr) * D_ + 32 + kg * 8);

  // ---- qrel[q][r] = Q-row q . rel_k[r] via MFMA (stride 112) ----
  for (int rt = w; rt < 7; rt += 4) {
    f32x4 c = (f32x4){0.f, 0.f, 0.f, 0.f};
    bf16x8 b0 = *(const bf16x8*)(relkB + (rt * 16 + fr) * 64 + kg * 8);
    bf16x8 b1 = *(const bf16x8*)(relkB + (rt * 16 + fr) * 64 + 32 + kg * 8);
    c = __builtin_amdgcn_mfma_f32_16x16x32_bf16(qa0, b0, c, 0, 0, 0);
    c = __builtin_amdgcn_mfma_f32_16x16x32_bf16(qa1, b1, c, 0, 0, 0);
#pragma unroll
    for (int rr = 0; rr < 4; ++rr)
      qrelp[(kg * 4 + rr) * 112 + rt * 16 + fr] = c[rr];
  }
  __syncthreads();

  // ---- QK^T into registers: c[j][rr] = score(q=kg*4+rr, k=j*64+w*16+fr) ----
  const int kbase = w * 16 + fr;
  f32x4 c[16];
#pragma unroll
  for (int j = 0; j < 16; ++j) {
    const unsigned short* kp = Kb + base + (size_t)(j * 64 + kbase) * D_ + kg * 8;
    bf16x8 kf0 = *(const bf16x8*)(kp);
    bf16x8 kf1 = *(const bf16x8*)(kp + 32);
    f32x4 t = (f32x4){0.f, 0.f, 0.f, 0.f};
    t = __builtin_amdgcn_mfma_f32_16x16x32_bf16(qa0, kf0, t, 0, 0, 0);
    t = __builtin_amdgcn_mfma_f32_16x16x32_bf16(qa1, kf1, t, 0, 0, 0);
    c[j] = t;
  }
  // bias + scale (in-register)
#pragma unroll
  for (int j = 0; j < 16; ++j) {
    const int k = j * 64 + kbase;
#pragma unroll
    for (int rr = 0; rr < 4; ++rr) {
      const int q = kg * 4 + rr;
      const int ridx = min(max(k - (q0 + q), -50), 50) + 50;
      c[j][rr] = (c[j][rr] + qrelp[q * 112 + ridx]) * 0.125f;
    }
  }

  // ---- in-register row max over this wave's 256 k, then cross-wave ----
  float mx[4];
#pragma unroll
  for (int rr = 0; rr < 4; ++rr) {
    float m = c[0][rr];
#pragma unroll
    for (int j = 1; j < 16; ++j) m = fmaxf(m, c[j][rr]);
#pragma unroll
    for (int o = 1; o <= 8; o <<= 1) m = fmaxf(m, __shfl_xor(m, o, 64));
    mx[rr] = m;
  }
  if (fr == 0) {
#pragma unroll
    for (int rr = 0; rr < 4; ++rr) redmx[(kg * 4 + rr) * 4 + w] = mx[rr];
  }
  __syncthreads();
  float m[4];
#pragma unroll
  for (int rr = 0; rr < 4; ++rr) {
    const int q = kg * 4 + rr;
    m[rr] = fmaxf(fmaxf(redmx[q * 4 + 0], redmx[q * 4 + 1]),
                  fmaxf(redmx[q * 4 + 2], redmx[q * 4 + 3]));
  }

  // ---- exp (in-register, unnormalized) ----
#pragma unroll
  for (int j = 0; j < 16; ++j)
#pragma unroll
    for (int rr = 0; rr < 4; ++rr) c[j][rr] = __expf(c[j][rr] - m[rr]);

  // ---- row sums + boundary bin sums (sL: dist<=-50, sR: dist>=50) ----
  float sm[4], sl[4], sr4[4];
#pragma unroll
  for (int rr = 0; rr < 4; ++rr) { sm[rr] = 0.f; sl[rr] = 0.f; sr4[rr] = 0.f; }
#pragma unroll
  for (int j = 0; j < 16; ++j) {
    const int k = j * 64 + kbase;
#pragma unroll
    for (int rr = 0; rr < 4; ++rr) {
      const int d = k - (q0 + kg * 4 + rr);
      const float e = c[j][rr];
      sm[rr] += e;
      sl[rr] += (d <= -50) ? e : 0.f;
      sr4[rr] += (d >= 50) ? e : 0.f;
    }
  }
#pragma unroll
  for (int rr = 0; rr < 4; ++rr) {
#pragma unroll
    for (int o = 1; o <= 8; o <<= 1) {
      sm[rr] += __shfl_xor(sm[rr], o, 64);
      sl[rr] += __shfl_xor(sl[rr], o, 64);
      sr4[rr] += __shfl_xor(sr4[rr], o, 64);
    }
  }
  if (fr == 0) {
#pragma unroll
    for (int rr = 0; rr < 4; ++rr) {
      const int q = kg * 4 + rr;
      redsm[q * 4 + w] = sm[rr];
      prp[q * 4 + w] = sl[rr];
      prp[64 + q * 4 + w] = sr4[rr];
    }
  }

  // ---- P write: bf16, swizzled granules (granule ^ (q&7) ^ ((q&8)>>2)) ----
#pragma unroll
  for (int j = 0; j < 16; ++j) {
    const int k = j * 64 + kbase;
    const int g = k >> 3, kl = k & 7;
#pragma unroll
    for (int rr = 0; rr < 4; ++rr) {
      const int q = kg * 4 + rr;
      const int swb = (q & 7) ^ ((q & 8) >> 2);
      Pb[q * 1024 + ((g ^ swb) << 3) + kl] = f2b(c[j][rr]);
    }
  }
  __syncthreads();

  // ---- prb: bf16 rel-bin table [16 q][136 r] (aliases dead qrelp buffer) ----
  // prb[q][r] = P[q][q0+q+r-50] for interior r; r=0 -> sL, r=100 -> sR; else 0.
  unsigned short* prb = (unsigned short*)qrelp;
  for (int e = tid; e < 16 * 136; e += 256) {
    const int q = e / 136, r = e - q * 136;
    unsigned short v = 0;
    if (r == 0) {
      v = f2b(prp[q * 4 + 0] + prp[q * 4 + 1] + prp[q * 4 + 2] + prp[q * 4 + 3]);
    } else if (r == 100) {
      v = f2b(prp[64 + q * 4 + 0] + prp[64 + q * 4 + 1] +
              prp[64 + q * 4 + 2] + prp[64 + q * 4 + 3]);
    } else if (r < 100) {
      const int k = q0 + q + r - 50;
      if (k >= 0 && k < S_) {
        const int swb = (q & 7) ^ ((q & 8) >> 2);
        v = Pb[q * 1024 + (((k >> 3) ^ swb) << 3) + (k & 7)];
      }
    }
    prb[q * 136 + r] = v;
  }
  __syncthreads();

  // ---- PV (O^T): A = vT rows (d), B = P rows (q=fr); unnormalized ----
  const int dtile = w * 16;
  const size_t vtb = ((size_t)(b * 1024 + h * 64 + dtile + fr)) * 1024;
  const int swbf = (fr & 7) ^ ((fr & 8) >> 2);
  const unsigned short* pbase = Pb + fr * 1024;
  f32x4 o = (f32x4){0.f, 0.f, 0.f, 0.f};
  __builtin_amdgcn_s_setprio(1);
#pragma unroll 8
  for (int ks = 0; ks < 32; ++ks) {
    bf16x8 va = *(const bf16x8*)(vT + vtb + ks * 32 + kg * 8);
    bf16x8 pb = *(const bf16x8*)(pbase + (((ks * 4 + kg) ^ swbf) << 3));
    o = __builtin_amdgcn_mfma_f32_16x16x32_bf16(va, pb, o, 0, 0, 0);
  }
  // ---- w2 (O^T): A = relvT rows (d), B = prb rows (q), K=128 in 4 steps ----
#pragma unroll
  for (int ks = 0; ks < 4; ++ks) {
    bf16x8 ra = *(const bf16x8*)(relvT + (dtile + fr) * 128 + ks * 32 + kg * 8);
    bf16x8 pv = *(const bf16x8*)(prb + fr * 136 + ks * 32 + kg * 8);
    o = __builtin_amdgcn_mfma_f32_16x16x32_bf16(ra, pv, o, 0, 0, 0);
  }
  __builtin_amdgcn_s_setprio(0);

  // ---- normalize + store ----
  const int q = fr;                    // col of O^T held by this lane
  const int dl = kg * 4;               // d rows dl..dl+3 within wave's d-tile
  const float rs = redsm[q * 4 + 0] + redsm[q * 4 + 1] +
                   redsm[q * 4 + 2] + redsm[q * 4 + 3];
  const float rinv = 1.f / rs;
  ushort4 st;
  st.x = f2b(o[0] * rinv);
  st.y = f2b(o[1] * rinv);
  st.z = f2b(o[2] * rinv);
  st.w = f2b(o[3] * rinv);
  *(ushort4*)(Wctx + base + (size_t)(q0 + q) * D_ + dtile + dl) = st;
}

// ---------------- launch ----------------
extern "C" void kernel_launch(void* const* d_in, const int* in_sizes, int n_in,
                              void* d_out, int out_size, void* d_ws, size_t ws_size,
                              hipStream_t stream) {
  (void)in_sizes; (void)n_in; (void)out_size;
  const float* x      = (const float*)d_in[0];
  const float* Wq     = (const float*)d_in[1];
  const float* bq     = (const float*)d_in[2];
  const float* Wk     = (const float*)d_in[3];
  const float* bk     = (const float*)d_in[4];
  const float* Wv     = (const float*)d_in[5];
  const float* bv     = (const float*)d_in[6];
  const float* Wo     = (const float*)d_in[7];
  const float* bo     = (const float*)d_in[8];
  const float* rel_k  = (const float*)d_in[9];
  const float* rel_v  = (const float*)d_in[10];
  const float* g_attn = (const float*)d_in[11];
  const float* g_ff   = (const float*)d_in[12];
  const float* W_in   = (const float*)d_in[13];
  const float* b_in   = (const float*)d_in[14];
  const float* W_out  = (const float*)d_in[15];
  const float* b_out  = (const float*)d_in[16];
  float* out = (float*)d_out;

  const size_t MB = 1u << 20;
  char* Wp = (char*)d_ws;
  float*          hbF  = (float*)Wp;                          // 16MB; later p0
  unsigned short* hbB  = (unsigned short*)(Wp + 16 * MB);     // 8MB
  unsigned short* qB   = (unsigned short*)(Wp + 24 * MB);     // 8MB
  unsigned short* kB   = (unsigned short*)(Wp + 32 * MB);     // 8MB
  unsigned short* vT   = (unsigned short*)(Wp + 40 * MB);     // 8MB  [b*1024+h*64+d][s]
  unsigned short* wB   = (unsigned short*)(Wp + 48 * MB);     // 8MB
  unsigned short* ff1B = (unsigned short*)(Wp + 24 * MB);     // 32MB overlay (qkv+w dead)
  float*          h2   = (float*)(Wp + 56 * MB);              // 16MB
  unsigned short* fB   = (unsigned short*)(Wp + 72 * MB);     // 8MB
  unsigned short* wqkvB= (unsigned short*)(Wp + 80 * MB);     // 6MB
  unsigned short* woB  = (unsigned short*)(Wp + 86 * MB);     // 2MB
  unsigned short* winB = (unsigned short*)(Wp + 88 * MB);     // 8MB
  unsigned short* woutB= (unsigned short*)(Wp + 96 * MB);     // 8MB
  unsigned short* relkB= (unsigned short*)(Wp + 104 * MB);    // 14KB
  float*          bqkvC= (float*)(Wp + 104 * MB + 16384);     // 12KB
  unsigned short* relvT= (unsigned short*)(Wp + 104 * MB + 32768);  // 16KB [64][128]
  float*          p0   = hbF;                                 // overlay (dead at FFN down)
  float*          p1   = (float*)(Wp + 105 * MB);             // 16MB (if ws allows)
  const bool splitK = (ws_size >= 121 * MB);

  // 0. all weight converts in one launch + bias concat (d2d async copies)
  hipLaunchKernelGGL(cvt_all, dim3(12303), dim3(256), 0, stream,
                     Wq, Wk, Wv, Wo, W_in, W_out, rel_k, rel_v,
                     wqkvB, woB, winB, woutB, relkB, relvT);
  hipMemcpyAsync(bqkvC,        bq, D_ * sizeof(float), hipMemcpyDeviceToDevice, stream);
  hipMemcpyAsync(bqkvC + D_,   bk, D_ * sizeof(float), hipMemcpyDeviceToDevice, stream);
  hipMemcpyAsync(bqkvC + 2*D_, bv, D_ * sizeof(float), hipMemcpyDeviceToDevice, stream);

  // 1. pre-norm + transpose -> hbB (bf16) + hbF (f32)
  hipLaunchKernelGGL((rmsnorm_kernel<true, true>), dim3(MROWS), dim3(256), 0, stream,
                     x, g_attn, hbB, hbF);
  // 2. fused QKV projection (Q,K row-major; V transposed per-head)
  hipLaunchKernelGGL((gemm_bf16<5>), dim3(MROWS / 128, 3072 / 128), dim3(256), 0, stream,
                     hbB, wqkvB, bqkvC, nullptr, qB, kB, vT, 3072, D_, 0, D_);
  // 3. MFMA relative attention (register scores + MFMA rel-v epilogue)
  hipLaunchKernelGGL(attn_mfma, dim3(4096), dim3(256), 0, stream,
                     qB, kB, vT, relkB, relvT, wB);
  // 4. O-proj + residual -> h2 (f32)
  hipLaunchKernelGGL((gemm_bf16<1>), dim3(MROWS / 128, D_ / 128), dim3(256), 0, stream,
                     wB, woB, bo, hbF, h2, nullptr, nullptr, D_, D_, 0, D_);
  // 5. second rmsnorm -> fB (bf16)
  hipLaunchKernelGGL((rmsnorm_kernel<false, false>), dim3(MROWS), dim3(256), 0, stream,
                     h2, g_ff, fB, nullptr);
  // 6. FFN up + gelu -> ff1B (bf16)
  hipLaunchKernelGGL((gemm_bf16<2>), dim3(MROWS / 128, DFF_ / 128), dim3(256), 0, stream,
                     fB, winB, b_in, nullptr, ff1B, nullptr, nullptr, DFF_, D_, 0, D_);
  // 7. FFN down + residual + transposed store
  if (splitK) {
    hipLaunchKernelGGL((gemm_bf16<6>), dim3(MROWS / 128, D_ / 128, 2), dim3(256), 0, stream,
                       ff1B, woutB, b_out, nullptr, p0, p1, nullptr, D_, DFF_, 0, DFF_ / 2);
    hipLaunchKernelGGL(combine_kernel, dim3(MROWS), dim3(256), 0, stream,
                       p0, p1, b_out, h2, out);
  } else {
    hipLaunchKernelGGL((gemm_bf16<3>), dim3(MROWS / 128, D_ / 128), dim3(256), 0, stream,
                       ff1B, woutB, b_out, h2, out, nullptr, nullptr, D_, DFF_, 0, DFF_);
  }
}